// Round 1
// baseline (611.638 us; speedup 1.0000x reference)
//
#include <hip/hip_runtime.h>
#include <math.h>

#define NN 10000
#define EE 320000
#define ET (EE + NN)   // 330000 edges incl. self-loops

// ---------------------------------------------------------------- CSR build
__global__ void k_count(const int* __restrict__ ei, int* __restrict__ cnt) {
  int e = blockIdx.x * 256 + threadIdx.x;
  if (e < EE) atomicAdd(&cnt[ei[EE + e]], 1);
}

// single-block exclusive scan of (cnt[n]+1); also places self-loop at slot 0
__global__ void k_scan(const int* __restrict__ cnt, int* __restrict__ rowst,
                       int* __restrict__ cursor, int* __restrict__ csrc) {
  __shared__ int sh[1024];
  int tid = threadIdx.x;
  int running = 0;
  for (int c0 = 0; c0 < NN; c0 += 1024) {
    int idx = c0 + tid;
    int v = (idx < NN) ? (cnt[idx] + 1) : 0;
    sh[tid] = v;
    __syncthreads();
    for (int off = 1; off < 1024; off <<= 1) {
      int t = (tid >= off) ? sh[tid - off] : 0;
      __syncthreads();
      sh[tid] += t;
      __syncthreads();
    }
    int excl = sh[tid] - v + running;
    if (idx < NN) {
      rowst[idx] = excl;
      csrc[excl] = idx;        // self-loop edge (src = dst = idx)
      cursor[idx] = excl + 1;  // real edges fill after the self-loop
    }
    running += sh[1023];
    __syncthreads();
  }
  if (tid == 0) rowst[NN] = running;  // == ET
}

__global__ void k_fill(const int* __restrict__ ei, int* __restrict__ cursor,
                       int* __restrict__ csrc) {
  int e = blockIdx.x * 256 + threadIdx.x;
  if (e < EE) {
    int d = ei[EE + e];
    int pos = atomicAdd(&cursor[d], 1);
    csrc[pos] = ei[e];
  }
}

// ---------------------------------------------------------------- GEMM (f32)
// C[M_rows x 256] = A[M_rows x K] * B[K x 256]
#define BM 64
#define BN 64
#define BK 32
__global__ void k_gemm(const float* __restrict__ A, const float* __restrict__ B,
                       float* __restrict__ Cout, int M_rows, int K) {
  __shared__ float As[BK][BM + 4];  // +4 keeps 16B row alignment for float4 reads
  __shared__ float Bs[BK][BN];
  int tid = threadIdx.x;
  int row0 = blockIdx.x * BM;
  int col0 = blockIdx.y * BN;
  int tx = tid & 15, ty = tid >> 4;
  float acc[4][4] = {};
  for (int k0 = 0; k0 < K; k0 += BK) {
#pragma unroll
    for (int i = 0; i < 8; i++) {  // A tile 64x32, transposed into LDS
      int e = i * 256 + tid;
      int m = e >> 5, kk = e & 31;
      int r = row0 + m;
      As[kk][m] = (r < M_rows) ? A[(size_t)r * K + k0 + kk] : 0.f;
    }
#pragma unroll
    for (int i = 0; i < 8; i++) {  // B tile 32x64
      int e = i * 256 + tid;
      int kk = e >> 6, c = e & 63;
      Bs[kk][c] = B[(size_t)(k0 + kk) * 256 + col0 + c];
    }
    __syncthreads();
#pragma unroll
    for (int kk = 0; kk < BK; kk++) {
      float4 a4 = *(const float4*)&As[kk][ty * 4];
      float4 b4 = *(const float4*)&Bs[kk][tx * 4];
      float av[4] = {a4.x, a4.y, a4.z, a4.w};
      float bv[4] = {b4.x, b4.y, b4.z, b4.w};
#pragma unroll
      for (int i = 0; i < 4; i++)
#pragma unroll
        for (int j = 0; j < 4; j++) acc[i][j] = fmaf(av[i], bv[j], acc[i][j]);
    }
    __syncthreads();
  }
#pragma unroll
  for (int i = 0; i < 4; i++) {
    int r = row0 + ty * 4 + i;
    if (r < M_rows) {
#pragma unroll
      for (int j = 0; j < 4; j++)
        Cout[(size_t)r * 256 + col0 + tx * 4 + j] = acc[i][j];
    }
  }
}

// ---------------------------------------------------------------- attention dots
// a_src[n][h] = <h[n,h,:], att_src[h,:]>, same for a_dst. One wave per (node,head).
template <int H, int C>
__global__ void k_att(const float* __restrict__ hbuf, const float* __restrict__ as,
                      const float* __restrict__ ad, float* __restrict__ asrc,
                      float* __restrict__ adst) {
  int g = (blockIdx.x * blockDim.x + threadIdx.x) >> 6;
  int lane = threadIdx.x & 63;
  if (g >= NN * H) return;
  int n = g / H, hd = g % H;
  float ps = 0.f, pd = 0.f;
  for (int c = lane; c < C; c += 64) {
    float v = hbuf[(size_t)n * 256 + hd * C + c];
    ps += v * as[hd * C + c];
    pd += v * ad[hd * C + c];
  }
#pragma unroll
  for (int off = 32; off > 0; off >>= 1) {
    ps += __shfl_xor(ps, off);
    pd += __shfl_xor(pd, off);
  }
  if (lane == 0) {
    asrc[n * H + hd] = ps;
    adst[n * H + hd] = pd;
  }
}

// ---------------------------------------------------------------- softmax stats
// one wave per dst node: segment max + unnormalized exp weights + denom
template <int H>
__global__ void k_stats(const int* __restrict__ rowst, const int* __restrict__ csrc,
                        const float* __restrict__ asrc, const float* __restrict__ adst,
                        float* __restrict__ wcsr, float* __restrict__ drow) {
  int g = (blockIdx.x * blockDim.x + threadIdx.x) >> 6;
  int lane = threadIdx.x & 63;
  if (g >= NN) return;
  int rs = rowst[g], re = rowst[g + 1];
  float ad[H], mx[H], sm[H];
#pragma unroll
  for (int h = 0; h < H; h++) {
    ad[h] = adst[g * H + h];
    mx[h] = -1e30f;
    sm[h] = 0.f;
  }
  for (int e = rs + lane; e < re; e += 64) {
    int s = csrc[e];
    float a[H];
    if (H == 4) {
      float4 av = ((const float4*)asrc)[s];
      a[0] = av.x; a[1] = av.y; a[2] = av.z; a[3] = av.w;
    } else {
      a[0] = asrc[s];
    }
#pragma unroll
    for (int h = 0; h < H; h++) {
      float al = a[h] + ad[h];
      al = al > 0.f ? al : 0.2f * al;
      mx[h] = fmaxf(mx[h], al);
    }
  }
#pragma unroll
  for (int off = 32; off > 0; off >>= 1)
#pragma unroll
    for (int h = 0; h < H; h++) mx[h] = fmaxf(mx[h], __shfl_xor(mx[h], off));
  for (int e = rs + lane; e < re; e += 64) {
    int s = csrc[e];
    float a[H];
    if (H == 4) {
      float4 av = ((const float4*)asrc)[s];
      a[0] = av.x; a[1] = av.y; a[2] = av.z; a[3] = av.w;
    } else {
      a[0] = asrc[s];
    }
    float w[H];
#pragma unroll
    for (int h = 0; h < H; h++) {
      float al = a[h] + ad[h];
      al = al > 0.f ? al : 0.2f * al;
      w[h] = expf(al - mx[h]);
      sm[h] += w[h];
    }
    if (H == 4) {
      float4 wv = make_float4(w[0], w[1], w[2], w[3]);
      ((float4*)wcsr)[e] = wv;
    } else {
      wcsr[e] = w[0];
    }
  }
#pragma unroll
  for (int off = 32; off > 0; off >>= 1)
#pragma unroll
    for (int h = 0; h < H; h++) sm[h] += __shfl_xor(sm[h], off);
  if (lane == 0) {
#pragma unroll
    for (int h = 0; h < H; h++) drow[g * H + h] = sm[h];
  }
}

// ---------------------------------------------------------------- aggregation
// one 256-thread block per dst node; thread t = channel t; coalesced h[src] rows
template <int H, int C>
__global__ void k_agg(const int* __restrict__ rowst, const int* __restrict__ csrc,
                      const float* __restrict__ hbuf, const float* __restrict__ wcsr,
                      const float* __restrict__ drow, const float* __restrict__ bias,
                      float* __restrict__ out) {
  int n = blockIdx.x;
  int t = threadIdx.x;
  int head = t / C;
  int rs = rowst[n], re = rowst[n + 1];
  float inv = 1.0f / (drow[n * H + head] + 1e-16f);
  float acc = 0.f;
  for (int e = rs; e < re; e++) {
    int s = csrc[e];
    acc = fmaf(wcsr[e * H + head], hbuf[(size_t)s * 256 + t], acc);
  }
  out[(size_t)n * 256 + t] = acc * inv + bias[t];
}

// ---------------------------------------------------------------- batch norm
__global__ void k_bnstats(const float* __restrict__ x, float* __restrict__ sums) {
  int t = threadIdx.x;
  int rows_per = (NN + gridDim.x - 1) / gridDim.x;
  int r0 = blockIdx.x * rows_per;
  int r1 = r0 + rows_per;
  if (r1 > NN) r1 = NN;
  float s = 0.f, ss = 0.f;
  for (int r = r0; r < r1; r++) {
    float v = x[(size_t)r * 256 + t];
    s += v;
    ss += v * v;
  }
  atomicAdd(&sums[t], s);
  atomicAdd(&sums[256 + t], ss);
}

__global__ void k_bnapply(const float* __restrict__ x, const float* __restrict__ sums,
                          const float* __restrict__ g, const float* __restrict__ be,
                          float* __restrict__ y, int relu) {
  int i = blockIdx.x * 256 + threadIdx.x;
  int c = threadIdx.x;  // 256 threads == 256 channels, block per row
  float m = sums[c] * (1.0f / NN);
  float v = sums[256 + c] * (1.0f / NN) - m * m;
  float val = (x[i] - m) * rsqrtf(v + 1e-5f) * g[c] + be[c];
  if (relu) val = fmaxf(val, 0.f);
  y[i] = val;
}

// ---------------------------------------------------------------- launch
extern "C" void kernel_launch(void* const* d_in, const int* in_sizes, int n_in,
                              void* d_out, int out_size, void* d_ws, size_t ws_size,
                              hipStream_t stream) {
  const float* x   = (const float*)d_in[0];
  const int*   ei  = (const int*)d_in[1];
  const float* W0  = (const float*)d_in[2];
  const float* as0 = (const float*)d_in[3];
  const float* ad0 = (const float*)d_in[4];
  const float* b0  = (const float*)d_in[5];
  const float* g0  = (const float*)d_in[6];
  const float* be0 = (const float*)d_in[7];
  const float* W1  = (const float*)d_in[8];
  const float* as1 = (const float*)d_in[9];
  const float* ad1 = (const float*)d_in[10];
  const float* b1  = (const float*)d_in[11];
  const float* g1  = (const float*)d_in[12];
  const float* be1 = (const float*)d_in[13];
  const float* W2  = (const float*)d_in[14];
  const float* as2 = (const float*)d_in[15];
  const float* ad2 = (const float*)d_in[16];
  const float* b2  = (const float*)d_in[17];
  const float* g2  = (const float*)d_in[18];
  const float* be2 = (const float*)d_in[19];
  float* out = (float*)d_out;

  // workspace layout (~27.7 MB)
  float* fws  = (float*)d_ws;
  float* hbuf = fws;                    // NN*256
  float* agg  = hbuf + (size_t)NN * 256;  // NN*256
  float* asrc = agg + (size_t)NN * 256;   // NN*4
  float* adst = asrc + NN * 4;          // NN*4
  float* drow = adst + NN * 4;          // NN*4
  float* wcsr = drow + NN * 4;          // ET*4
  float* bns  = wcsr + (size_t)ET * 4;  // 3*512
  int* cnt    = (int*)(bns + 3 * 512);  // NN
  int* rowst  = cnt + NN;               // NN+1
  int* cursor = rowst + NN + 1;         // NN
  int* csrc   = cursor + NN;            // ET

  // ---- CSR build (re-done every call; inputs identical each call)
  hipMemsetAsync(cnt, 0, NN * sizeof(int), stream);
  hipMemsetAsync(bns, 0, 3 * 512 * sizeof(float), stream);
  k_count<<<(EE + 255) / 256, 256, 0, stream>>>(ei, cnt);
  k_scan<<<1, 1024, 0, stream>>>(cnt, rowst, cursor, csrc);
  k_fill<<<(EE + 255) / 256, 256, 0, stream>>>(ei, cursor, csrc);

  dim3 ggrid((NN + BM - 1) / BM, 256 / BN);

  // ---- layer 0: GAT(128 -> 4x64) + BN + ReLU
  k_gemm<<<ggrid, 256, 0, stream>>>(x, W0, hbuf, NN, 128);
  k_att<4, 64><<<(NN * 4) / 4, 256, 0, stream>>>(hbuf, as0, ad0, asrc, adst);
  k_stats<4><<<(NN + 3) / 4, 256, 0, stream>>>(rowst, csrc, asrc, adst, wcsr, drow);
  k_agg<4, 64><<<NN, 256, 0, stream>>>(rowst, csrc, hbuf, wcsr, drow, b0, agg);
  k_bnstats<<<80, 256, 0, stream>>>(agg, bns);
  k_bnapply<<<NN, 256, 0, stream>>>(agg, bns, g0, be0, agg, 1);

  // ---- layer 1: GAT(256 -> 4x64) + BN + ReLU
  k_gemm<<<ggrid, 256, 0, stream>>>(agg, W1, hbuf, NN, 256);
  k_att<4, 64><<<(NN * 4) / 4, 256, 0, stream>>>(hbuf, as1, ad1, asrc, adst);
  k_stats<4><<<(NN + 3) / 4, 256, 0, stream>>>(rowst, csrc, asrc, adst, wcsr, drow);
  k_agg<4, 64><<<NN, 256, 0, stream>>>(rowst, csrc, hbuf, wcsr, drow, b1, agg);
  k_bnstats<<<80, 256, 0, stream>>>(agg, bns + 512);
  k_bnapply<<<NN, 256, 0, stream>>>(agg, bns + 512, g1, be1, agg, 1);

  // ---- layer 2: GAT(256 -> 256, heads=1) + BN
  k_gemm<<<ggrid, 256, 0, stream>>>(agg, W2, hbuf, NN, 256);
  k_att<1, 256><<<(NN + 3) / 4, 256, 0, stream>>>(hbuf, as2, ad2, asrc, adst);
  k_stats<1><<<(NN + 3) / 4, 256, 0, stream>>>(rowst, csrc, asrc, adst, wcsr, drow);
  k_agg<1, 256><<<NN, 256, 0, stream>>>(rowst, csrc, hbuf, wcsr, drow, b2, agg);
  k_bnstats<<<80, 256, 0, stream>>>(agg, bns + 1024);
  k_bnapply<<<NN, 256, 0, stream>>>(agg, bns + 1024, g2, be2, out, 0);
}

// Round 2
// 506.905 us; speedup vs baseline: 1.2066x; 1.2066x over previous
//
#include <hip/hip_runtime.h>
#include <math.h>

#define NN 10000
#define EE 320000
#define ET (EE + NN)   // 330000 edges incl. self-loops

// ---------------------------------------------------------------- CSR build
__global__ void k_count(const int* __restrict__ ei, int* __restrict__ cnt) {
  int e = blockIdx.x * 256 + threadIdx.x;
  if (e < EE) atomicAdd(&cnt[ei[EE + e]], 1);
}

// single-block exclusive scan of (cnt[n]+1); also places self-loop at slot 0
__global__ void k_scan(const int* __restrict__ cnt, int* __restrict__ rowst,
                       int* __restrict__ cursor, int* __restrict__ csrc) {
  __shared__ int sh[1024];
  int tid = threadIdx.x;
  int running = 0;
  for (int c0 = 0; c0 < NN; c0 += 1024) {
    int idx = c0 + tid;
    int v = (idx < NN) ? (cnt[idx] + 1) : 0;
    sh[tid] = v;
    __syncthreads();
    for (int off = 1; off < 1024; off <<= 1) {
      int t = (tid >= off) ? sh[tid - off] : 0;
      __syncthreads();
      sh[tid] += t;
      __syncthreads();
    }
    int excl = sh[tid] - v + running;
    if (idx < NN) {
      rowst[idx] = excl;
      csrc[excl] = idx;        // self-loop edge (src = dst = idx)
      cursor[idx] = excl + 1;  // real edges fill after the self-loop
    }
    running += sh[1023];
    __syncthreads();
  }
  if (tid == 0) rowst[NN] = running;  // == ET
}

__global__ void k_fill(const int* __restrict__ ei, int* __restrict__ cursor,
                       int* __restrict__ csrc) {
  int e = blockIdx.x * 256 + threadIdx.x;
  if (e < EE) {
    int d = ei[EE + e];
    int pos = atomicAdd(&cursor[d], 1);
    csrc[pos] = ei[e];
  }
}

// ---------------------------------------------------------------- GEMM (f32)
// C[M_rows x 256] = A[M_rows x K] * B[K x 256]
#define BM 64
#define BN 64
#define BK 32
__global__ void k_gemm(const float* __restrict__ A, const float* __restrict__ B,
                       float* __restrict__ Cout, int M_rows, int K) {
  __shared__ float As[BK][BM + 4];
  __shared__ float Bs[BK][BN];
  int tid = threadIdx.x;
  int row0 = blockIdx.x * BM;
  int col0 = blockIdx.y * BN;
  int tx = tid & 15, ty = tid >> 4;
  float acc[4][4] = {};
  for (int k0 = 0; k0 < K; k0 += BK) {
#pragma unroll
    for (int i = 0; i < 8; i++) {  // A tile 64x32, transposed into LDS
      int e = i * 256 + tid;
      int m = e >> 5, kk = e & 31;
      int r = row0 + m;
      As[kk][m] = (r < M_rows) ? A[(size_t)r * K + k0 + kk] : 0.f;
    }
#pragma unroll
    for (int i = 0; i < 8; i++) {  // B tile 32x64
      int e = i * 256 + tid;
      int kk = e >> 6, c = e & 63;
      Bs[kk][c] = B[(size_t)(k0 + kk) * 256 + col0 + c];
    }
    __syncthreads();
#pragma unroll
    for (int kk = 0; kk < BK; kk++) {
      float4 a4 = *(const float4*)&As[kk][ty * 4];
      float4 b4 = *(const float4*)&Bs[kk][tx * 4];
      float av[4] = {a4.x, a4.y, a4.z, a4.w};
      float bv[4] = {b4.x, b4.y, b4.z, b4.w};
#pragma unroll
      for (int i = 0; i < 4; i++)
#pragma unroll
        for (int j = 0; j < 4; j++) acc[i][j] = fmaf(av[i], bv[j], acc[i][j]);
    }
    __syncthreads();
  }
#pragma unroll
  for (int i = 0; i < 4; i++) {
    int r = row0 + ty * 4 + i;
    if (r < M_rows) {
#pragma unroll
      for (int j = 0; j < 4; j++)
        Cout[(size_t)r * 256 + col0 + tx * 4 + j] = acc[i][j];
    }
  }
}

// ---------------------------------------------------------------- attention dots
// one wave per node; lane owns 4 channels (float4); group-reduce per head
template <int H>
__global__ void k_att(const float* __restrict__ hbuf, const float* __restrict__ as,
                      const float* __restrict__ ad, float* __restrict__ asrc,
                      float* __restrict__ adst) {
  int n = blockIdx.x * 4 + (threadIdx.x >> 6);
  int lane = threadIdx.x & 63;
  if (n >= NN) return;
  float4 v = ((const float4*)hbuf)[(size_t)n * 64 + lane];
  float4 sa = ((const float4*)as)[lane];
  float4 da = ((const float4*)ad)[lane];
  float ps = v.x * sa.x + v.y * sa.y + v.z * sa.z + v.w * sa.w;
  float pd = v.x * da.x + v.y * da.y + v.z * da.z + v.w * da.w;
  const int G = (H == 4) ? 16 : 64;
#pragma unroll
  for (int off = 1; off < G; off <<= 1) {
    ps += __shfl_xor(ps, off);
    pd += __shfl_xor(pd, off);
  }
  if ((lane & (G - 1)) == 0) {
    int hd = lane / G;
    asrc[n * H + hd] = ps;
    adst[n * H + hd] = pd;
  }
}

// ---------------------------------------------------------------- softmax
// one wave per node: gather asrc once, logits for first 128 edges stay in
// registers (named a0/a1 — static indexing), spill path beyond (deg>128 never
// happens here but kept correct). Writes NORMALIZED weights.
template <int H>
__global__ void k_soft(const int* __restrict__ rowst, const int* __restrict__ csrc,
                       const float* __restrict__ asrc, const float* __restrict__ adst,
                       float* __restrict__ wcsr) {
  int n = blockIdx.x * 4 + (threadIdx.x >> 6);
  int lane = threadIdx.x & 63;
  if (n >= NN) return;
  int rs = rowst[n], re = rowst[n + 1];
  float ad[H];
#pragma unroll
  for (int h = 0; h < H; h++) ad[h] = adst[n * H + h];

  float mx[H], sm[H];
#pragma unroll
  for (int h = 0; h < H; h++) { mx[h] = -1e30f; sm[h] = 0.f; }

  int e0 = rs + lane, e1 = e0 + 64;
  bool has0 = e0 < re, has1 = e1 < re;
  float a0[H], a1[H];

  // ---- pass 1: gather + leaky-relu + max
  if (has0) {
    if (H == 4) {
      float4 av = ((const float4*)asrc)[csrc[e0]];
      a0[0] = av.x; a0[1] = av.y; a0[2] = av.z; a0[3] = av.w;
    } else a0[0] = asrc[csrc[e0]];
#pragma unroll
    for (int h = 0; h < H; h++) {
      float v = a0[h] + ad[h];
      v = v > 0.f ? v : 0.2f * v;
      a0[h] = v;
      mx[h] = fmaxf(mx[h], v);
    }
  }
  if (has1) {
    if (H == 4) {
      float4 av = ((const float4*)asrc)[csrc[e1]];
      a1[0] = av.x; a1[1] = av.y; a1[2] = av.z; a1[3] = av.w;
    } else a1[0] = asrc[csrc[e1]];
#pragma unroll
    for (int h = 0; h < H; h++) {
      float v = a1[h] + ad[h];
      v = v > 0.f ? v : 0.2f * v;
      a1[h] = v;
      mx[h] = fmaxf(mx[h], v);
    }
  }
  for (int e = rs + lane + 128; e < re; e += 64) {  // rare spill path
    float a[H];
    if (H == 4) {
      float4 av = ((const float4*)asrc)[csrc[e]];
      a[0] = av.x; a[1] = av.y; a[2] = av.z; a[3] = av.w;
    } else a[0] = asrc[csrc[e]];
#pragma unroll
    for (int h = 0; h < H; h++) {
      float v = a[h] + ad[h];
      v = v > 0.f ? v : 0.2f * v;
      a[h] = v;
      mx[h] = fmaxf(mx[h], v);
    }
    if (H == 4) ((float4*)wcsr)[e] = make_float4(a[0], a[1], a[2], a[3]);
    else wcsr[e] = a[0];
  }
#pragma unroll
  for (int off = 32; off; off >>= 1)
#pragma unroll
    for (int h = 0; h < H; h++) mx[h] = fmaxf(mx[h], __shfl_xor(mx[h], off));

  // ---- pass 2: exp + sum
  if (has0) {
#pragma unroll
    for (int h = 0; h < H; h++) { a0[h] = __expf(a0[h] - mx[h]); sm[h] += a0[h]; }
  }
  if (has1) {
#pragma unroll
    for (int h = 0; h < H; h++) { a1[h] = __expf(a1[h] - mx[h]); sm[h] += a1[h]; }
  }
  for (int e = rs + lane + 128; e < re; e += 64) {
    float a[H];
    if (H == 4) {
      float4 av = ((const float4*)wcsr)[e];
      a[0] = av.x; a[1] = av.y; a[2] = av.z; a[3] = av.w;
    } else a[0] = wcsr[e];
#pragma unroll
    for (int h = 0; h < H; h++) { a[h] = __expf(a[h] - mx[h]); sm[h] += a[h]; }
    if (H == 4) ((float4*)wcsr)[e] = make_float4(a[0], a[1], a[2], a[3]);
    else wcsr[e] = a[0];
  }
#pragma unroll
  for (int off = 32; off; off >>= 1)
#pragma unroll
    for (int h = 0; h < H; h++) sm[h] += __shfl_xor(sm[h], off);

  float inv[H];
#pragma unroll
  for (int h = 0; h < H; h++) inv[h] = 1.0f / (sm[h] + 1e-16f);

  // ---- pass 3: write normalized weights
  if (has0) {
    if (H == 4) ((float4*)wcsr)[e0] =
        make_float4(a0[0] * inv[0], a0[1] * inv[1], a0[2] * inv[2], a0[3] * inv[3]);
    else wcsr[e0] = a0[0] * inv[0];
  }
  if (has1) {
    if (H == 4) ((float4*)wcsr)[e1] =
        make_float4(a1[0] * inv[0], a1[1] * inv[1], a1[2] * inv[2], a1[3] * inv[3]);
    else wcsr[e1] = a1[0] * inv[0];
  }
  for (int e = rs + lane + 128; e < re; e += 64) {
    if (H == 4) {
      float4 av = ((const float4*)wcsr)[e];
      ((float4*)wcsr)[e] =
          make_float4(av.x * inv[0], av.y * inv[1], av.z * inv[2], av.w * inv[3]);
    } else wcsr[e] = wcsr[e] * inv[0];
  }
}

// ---------------------------------------------------------------- aggregation
// one wave per node; lane owns 4 channels; edge loop unrolled x4 (4 independent
// 16B gathers in flight per lane); weights pre-normalized.
template <int H>
__global__ void k_agg(const int* __restrict__ rowst, const int* __restrict__ csrc,
                      const float* __restrict__ hbuf, const float* __restrict__ wn,
                      const float* __restrict__ bias, float* __restrict__ out) {
  int n = blockIdx.x * 4 + (threadIdx.x >> 6);
  int lane = threadIdx.x & 63;
  if (n >= NN) return;
  int rs = rowst[n], re = rowst[n + 1];
  int head = (H == 4) ? (lane >> 4) : 0;
  const float4* h4 = (const float4*)hbuf;
  float4 acc0 = {0.f, 0.f, 0.f, 0.f}, acc1 = {0.f, 0.f, 0.f, 0.f};
  int e = rs;
  for (; e + 4 <= re; e += 4) {
    int s0 = csrc[e], s1 = csrc[e + 1], s2 = csrc[e + 2], s3 = csrc[e + 3];
    float w0 = wn[e * H + head];
    float w1 = wn[(e + 1) * H + head];
    float w2 = wn[(e + 2) * H + head];
    float w3 = wn[(e + 3) * H + head];
    float4 v0 = h4[(size_t)s0 * 64 + lane];
    float4 v1 = h4[(size_t)s1 * 64 + lane];
    float4 v2 = h4[(size_t)s2 * 64 + lane];
    float4 v3 = h4[(size_t)s3 * 64 + lane];
    acc0.x = fmaf(w0, v0.x, acc0.x); acc0.y = fmaf(w0, v0.y, acc0.y);
    acc0.z = fmaf(w0, v0.z, acc0.z); acc0.w = fmaf(w0, v0.w, acc0.w);
    acc1.x = fmaf(w1, v1.x, acc1.x); acc1.y = fmaf(w1, v1.y, acc1.y);
    acc1.z = fmaf(w1, v1.z, acc1.z); acc1.w = fmaf(w1, v1.w, acc1.w);
    acc0.x = fmaf(w2, v2.x, acc0.x); acc0.y = fmaf(w2, v2.y, acc0.y);
    acc0.z = fmaf(w2, v2.z, acc0.z); acc0.w = fmaf(w2, v2.w, acc0.w);
    acc1.x = fmaf(w3, v3.x, acc1.x); acc1.y = fmaf(w3, v3.y, acc1.y);
    acc1.z = fmaf(w3, v3.z, acc1.z); acc1.w = fmaf(w3, v3.w, acc1.w);
  }
  for (; e < re; e++) {
    int s = csrc[e];
    float w = wn[e * H + head];
    float4 v = h4[(size_t)s * 64 + lane];
    acc0.x = fmaf(w, v.x, acc0.x); acc0.y = fmaf(w, v.y, acc0.y);
    acc0.z = fmaf(w, v.z, acc0.z); acc0.w = fmaf(w, v.w, acc0.w);
  }
  float4 b4 = ((const float4*)bias)[lane];
  float4 r;
  r.x = acc0.x + acc1.x + b4.x;
  r.y = acc0.y + acc1.y + b4.y;
  r.z = acc0.z + acc1.z + b4.z;
  r.w = acc0.w + acc1.w + b4.w;
  ((float4*)out)[(size_t)n * 64 + lane] = r;
}

// ---------------------------------------------------------------- batch norm
__global__ void k_bnstats(const float* __restrict__ x, float* __restrict__ sums) {
  int t = threadIdx.x;
  int rows_per = (NN + gridDim.x - 1) / gridDim.x;
  int r0 = blockIdx.x * rows_per;
  int r1 = r0 + rows_per;
  if (r1 > NN) r1 = NN;
  float s = 0.f, ss = 0.f;
  for (int r = r0; r < r1; r++) {
    float v = x[(size_t)r * 256 + t];
    s += v;
    ss += v * v;
  }
  atomicAdd(&sums[t], s);
  atomicAdd(&sums[256 + t], ss);
}

__global__ void k_bnapply(const float* __restrict__ x, const float* __restrict__ sums,
                          const float* __restrict__ g, const float* __restrict__ be,
                          float* __restrict__ y, int relu) {
  int i = blockIdx.x * 256 + threadIdx.x;
  int c = threadIdx.x;
  float m = sums[c] * (1.0f / NN);
  float v = sums[256 + c] * (1.0f / NN) - m * m;
  float val = (x[i] - m) * rsqrtf(v + 1e-5f) * g[c] + be[c];
  if (relu) val = fmaxf(val, 0.f);
  y[i] = val;
}

// ---------------------------------------------------------------- launch
extern "C" void kernel_launch(void* const* d_in, const int* in_sizes, int n_in,
                              void* d_out, int out_size, void* d_ws, size_t ws_size,
                              hipStream_t stream) {
  const float* x   = (const float*)d_in[0];
  const int*   ei  = (const int*)d_in[1];
  const float* W0  = (const float*)d_in[2];
  const float* as0 = (const float*)d_in[3];
  const float* ad0 = (const float*)d_in[4];
  const float* b0  = (const float*)d_in[5];
  const float* g0  = (const float*)d_in[6];
  const float* be0 = (const float*)d_in[7];
  const float* W1  = (const float*)d_in[8];
  const float* as1 = (const float*)d_in[9];
  const float* ad1 = (const float*)d_in[10];
  const float* b1  = (const float*)d_in[11];
  const float* g1  = (const float*)d_in[12];
  const float* be1 = (const float*)d_in[13];
  const float* W2  = (const float*)d_in[14];
  const float* as2 = (const float*)d_in[15];
  const float* ad2 = (const float*)d_in[16];
  const float* b2  = (const float*)d_in[17];
  const float* g2  = (const float*)d_in[18];
  const float* be2 = (const float*)d_in[19];
  float* out = (float*)d_out;

  // workspace layout
  float* fws  = (float*)d_ws;
  float* hbuf = fws;                      // NN*256
  float* agg  = hbuf + (size_t)NN * 256;  // NN*256
  float* asrc = agg + (size_t)NN * 256;   // NN*4
  float* adst = asrc + NN * 4;            // NN*4
  float* wcsr = adst + NN * 4;            // ET*4
  float* bns  = wcsr + (size_t)ET * 4;    // 3*512
  int* cnt    = (int*)(bns + 3 * 512);    // NN
  int* rowst  = cnt + NN;                 // NN+1
  int* cursor = rowst + NN + 1;           // NN
  int* csrc   = cursor + NN;              // ET

  // ---- CSR build
  hipMemsetAsync(cnt, 0, NN * sizeof(int), stream);
  hipMemsetAsync(bns, 0, 3 * 512 * sizeof(float), stream);
  k_count<<<(EE + 255) / 256, 256, 0, stream>>>(ei, cnt);
  k_scan<<<1, 1024, 0, stream>>>(cnt, rowst, cursor, csrc);
  k_fill<<<(EE + 255) / 256, 256, 0, stream>>>(ei, cursor, csrc);

  dim3 ggrid((NN + BM - 1) / BM, 256 / BN);
  int ngrid = (NN + 3) / 4;

  // ---- layer 0: GAT(128 -> 4x64) + BN + ReLU
  k_gemm<<<ggrid, 256, 0, stream>>>(x, W0, hbuf, NN, 128);
  k_att<4><<<ngrid, 256, 0, stream>>>(hbuf, as0, ad0, asrc, adst);
  k_soft<4><<<ngrid, 256, 0, stream>>>(rowst, csrc, asrc, adst, wcsr);
  k_agg<4><<<ngrid, 256, 0, stream>>>(rowst, csrc, hbuf, wcsr, b0, agg);
  k_bnstats<<<80, 256, 0, stream>>>(agg, bns);
  k_bnapply<<<NN, 256, 0, stream>>>(agg, bns, g0, be0, agg, 1);

  // ---- layer 1: GAT(256 -> 4x64) + BN + ReLU
  k_gemm<<<ggrid, 256, 0, stream>>>(agg, W1, hbuf, NN, 256);
  k_att<4><<<ngrid, 256, 0, stream>>>(hbuf, as1, ad1, asrc, adst);
  k_soft<4><<<ngrid, 256, 0, stream>>>(rowst, csrc, asrc, adst, wcsr);
  k_agg<4><<<ngrid, 256, 0, stream>>>(rowst, csrc, hbuf, wcsr, b1, agg);
  k_bnstats<<<80, 256, 0, stream>>>(agg, bns + 512);
  k_bnapply<<<NN, 256, 0, stream>>>(agg, bns + 512, g1, be1, agg, 1);

  // ---- layer 2: GAT(256 -> 256, heads=1) + BN
  k_gemm<<<ggrid, 256, 0, stream>>>(agg, W2, hbuf, NN, 256);
  k_att<1><<<ngrid, 256, 0, stream>>>(hbuf, as2, ad2, asrc, adst);
  k_soft<1><<<ngrid, 256, 0, stream>>>(rowst, csrc, asrc, adst, wcsr);
  k_agg<1><<<ngrid, 256, 0, stream>>>(rowst, csrc, hbuf, wcsr, b2, agg);
  k_bnstats<<<80, 256, 0, stream>>>(agg, bns + 1024);
  k_bnapply<<<NN, 256, 0, stream>>>(agg, bns + 1024, g2, be2, out, 0);
}

// Round 3
// 417.544 us; speedup vs baseline: 1.4648x; 1.2140x over previous
//
#include <hip/hip_runtime.h>
#include <math.h>

#define NN 10000
#define EE 320000
#define ET (EE + NN)   // 330000 edges incl. self-loops

typedef __attribute__((ext_vector_type(8))) short short8;   // 8 x bf16 (4 VGPR)
typedef __attribute__((ext_vector_type(4))) float f32x4;
typedef unsigned short u16;

static __device__ __forceinline__ float b2f(u16 u) {
  return __uint_as_float(((unsigned)u) << 16);
}
static __device__ __forceinline__ u16 f2b(float f) {
  unsigned u = __float_as_uint(f);
  unsigned r = (u + 0x7FFFu + ((u >> 16) & 1u)) >> 16;  // RNE
  return (u16)r;
}

// ---------------------------------------------------------------- CSR build
__global__ void k_count(const int* __restrict__ ei, int* __restrict__ cnt) {
  int e = blockIdx.x * 256 + threadIdx.x;
  if (e < EE) atomicAdd(&cnt[ei[EE + e]], 1);
}

// single-block scan: 10 elems/thread + wave shfl scan + 16-wave LDS scan
__global__ __launch_bounds__(1024) void k_scan(const int* __restrict__ cnt,
                                               int* __restrict__ rowst,
                                               int* __restrict__ cursor,
                                               int* __restrict__ csrc) {
  __shared__ int ws[16];
  int tid = threadIdx.x, lane = tid & 63, wv = tid >> 6;
  int base = tid * 10;
  int v[10];
  int tot = 0;
#pragma unroll
  for (int i = 0; i < 10; i++) {
    int idx = base + i;
    v[i] = (idx < NN) ? (cnt[idx] + 1) : 0;
    tot += v[i];
  }
  int sc = tot;  // wave inclusive scan
#pragma unroll
  for (int off = 1; off < 64; off <<= 1) {
    int t = __shfl_up(sc, off);
    if (lane >= off) sc += t;
  }
  if (lane == 63) ws[wv] = sc;
  __syncthreads();
  if (wv == 0 && lane < 16) {
    int val = ws[lane];
    int s = val;
#pragma unroll
    for (int off = 1; off < 16; off <<= 1) {
      int t = __shfl_up(s, off);
      if (lane >= off) s += t;
    }
    ws[lane] = s - val;  // exclusive wave offset
  }
  __syncthreads();
  int run = ws[wv] + sc - tot;  // this thread's exclusive start
#pragma unroll
  for (int i = 0; i < 10; i++) {
    int idx = base + i;
    if (idx < NN) {
      rowst[idx] = run;
      csrc[run] = idx;        // self-loop at slot 0
      cursor[idx] = run + 1;  // real edges after it
      run += v[i];
    }
  }
  if (tid == 1023) rowst[NN] = run;  // == ET
}

__global__ void k_fill(const int* __restrict__ ei, int* __restrict__ cursor,
                       int* __restrict__ csrc) {
  int e = blockIdx.x * 256 + threadIdx.x;
  if (e < EE) {
    int d = ei[EE + e];
    int pos = atomicAdd(&cursor[d], 1);
    csrc[pos] = ei[e];
  }
}

// ---------------------------------------------------------------- casts
__global__ void k_cast4(const float* __restrict__ in, u16* __restrict__ out, int n4) {
  int i = blockIdx.x * 256 + threadIdx.x;
  if (i < n4) {
    float4 f = ((const float4*)in)[i];
    ushort4 o;
    o.x = f2b(f.x); o.y = f2b(f.y); o.z = f2b(f.z); o.w = f2b(f.w);
    ((ushort4*)out)[i] = o;
  }
}

// Wt[n][k] = W[k][n], bf16. W is [K][256].
__global__ void k_castW(const float* __restrict__ W, u16* __restrict__ Wt, int K) {
  int t = blockIdx.x * 256 + threadIdx.x;
  if (t < K * 256) {
    int nIdx = t / K, k = t - nIdx * K;
    Wt[t] = f2b(W[(size_t)k * 256 + nIdx]);
  }
}

// ---------------------------------------------------------------- MFMA GEMM
// hb[M x 256] (bf16) = A[M x KK] (bf16) * Wt^T, Wt is [256 x KK] (B^T layout).
// Block: 256 thr = 4 waves, 64 rows x 64 cols. No LDS: B-strip (32KB) is
// L1/L2-resident; A-frags are direct 16B global loads.
template <int KK>
__global__ __launch_bounds__(256) void k_gemm(const u16* __restrict__ A,
                                              const u16* __restrict__ Wt,
                                              u16* __restrict__ hb) {
  int wv = threadIdx.x >> 6, lane = threadIdx.x & 63;
  int row0 = blockIdx.x * 64 + wv * 16;
  int col0 = blockIdx.y * 64;
  int r = lane & 15, g = lane >> 4;
  f32x4 acc[4];
#pragma unroll
  for (int nt = 0; nt < 4; nt++) acc[nt] = (f32x4){0.f, 0.f, 0.f, 0.f};

  int ar = row0 + r;
  if (ar > NN - 1) ar = NN - 1;  // clamp (stores are guarded)
  const u16* Arow = A + (size_t)ar * KK + g * 8;

#pragma unroll
  for (int ks = 0; ks < KK / 32; ks++) {
    short8 af = *(const short8*)(Arow + ks * 32);
#pragma unroll
    for (int nt = 0; nt < 4; nt++) {
      short8 bf = *(const short8*)(Wt + (size_t)(col0 + nt * 16 + r) * KK + ks * 32 + g * 8);
      acc[nt] = __builtin_amdgcn_mfma_f32_16x16x32_bf16(af, bf, acc[nt], 0, 0, 0);
    }
  }
  // C/D: col = lane&15, row = (lane>>4)*4 + reg   [m89/m91]
#pragma unroll
  for (int nt = 0; nt < 4; nt++) {
    int col = col0 + nt * 16 + r;
#pragma unroll
    for (int q = 0; q < 4; q++) {
      int row = row0 + g * 4 + q;
      if (row < NN) hb[(size_t)row * 256 + col] = f2b(acc[nt][q]);
    }
  }
}

// ---------------------------------------------------------------- attention dots
// one wave per node; lane owns 4 channels (bf16x4); group-reduce per head
template <int H>
__global__ void k_att(const u16* __restrict__ hb, const float* __restrict__ as,
                      const float* __restrict__ ad, float* __restrict__ asrc,
                      float* __restrict__ adst) {
  int n = blockIdx.x * 4 + (threadIdx.x >> 6);
  int lane = threadIdx.x & 63;
  if (n >= NN) return;
  ushort4 u = ((const ushort4*)hb)[(size_t)n * 64 + lane];
  float4 sa = ((const float4*)as)[lane];
  float4 da = ((const float4*)ad)[lane];
  float vx = b2f(u.x), vy = b2f(u.y), vz = b2f(u.z), vw = b2f(u.w);
  float ps = vx * sa.x + vy * sa.y + vz * sa.z + vw * sa.w;
  float pd = vx * da.x + vy * da.y + vz * da.z + vw * da.w;
  const int G = (H == 4) ? 16 : 64;
#pragma unroll
  for (int off = 1; off < G; off <<= 1) {
    ps += __shfl_xor(ps, off);
    pd += __shfl_xor(pd, off);
  }
  if ((lane & (G - 1)) == 0) {
    int hd = lane / G;
    asrc[n * H + hd] = ps;
    adst[n * H + hd] = pd;
  }
}

// ---------------------------------------------------------------- softmax
// one wave per node; logits for first 128 edges in named regs; writes
// NORMALIZED weights.
template <int H>
__global__ void k_soft(const int* __restrict__ rowst, const int* __restrict__ csrc,
                       const float* __restrict__ asrc, const float* __restrict__ adst,
                       float* __restrict__ wcsr) {
  int n = blockIdx.x * 4 + (threadIdx.x >> 6);
  int lane = threadIdx.x & 63;
  if (n >= NN) return;
  int rs = rowst[n], re = rowst[n + 1];
  float ad[H];
#pragma unroll
  for (int h = 0; h < H; h++) ad[h] = adst[n * H + h];

  float mx[H], sm[H];
#pragma unroll
  for (int h = 0; h < H; h++) { mx[h] = -1e30f; sm[h] = 0.f; }

  int e0 = rs + lane, e1 = e0 + 64;
  bool has0 = e0 < re, has1 = e1 < re;
  float a0[H], a1[H];

  if (has0) {
    if (H == 4) {
      float4 av = ((const float4*)asrc)[csrc[e0]];
      a0[0] = av.x; a0[1] = av.y; a0[2] = av.z; a0[3] = av.w;
    } else a0[0] = asrc[csrc[e0]];
#pragma unroll
    for (int h = 0; h < H; h++) {
      float v = a0[h] + ad[h];
      v = v > 0.f ? v : 0.2f * v;
      a0[h] = v;
      mx[h] = fmaxf(mx[h], v);
    }
  }
  if (has1) {
    if (H == 4) {
      float4 av = ((const float4*)asrc)[csrc[e1]];
      a1[0] = av.x; a1[1] = av.y; a1[2] = av.z; a1[3] = av.w;
    } else a1[0] = asrc[csrc[e1]];
#pragma unroll
    for (int h = 0; h < H; h++) {
      float v = a1[h] + ad[h];
      v = v > 0.f ? v : 0.2f * v;
      a1[h] = v;
      mx[h] = fmaxf(mx[h], v);
    }
  }
  for (int e = rs + lane + 128; e < re; e += 64) {  // rare spill path
    float a[H];
    if (H == 4) {
      float4 av = ((const float4*)asrc)[csrc[e]];
      a[0] = av.x; a[1] = av.y; a[2] = av.z; a[3] = av.w;
    } else a[0] = asrc[csrc[e]];
#pragma unroll
    for (int h = 0; h < H; h++) {
      float v = a[h] + ad[h];
      v = v > 0.f ? v : 0.2f * v;
      a[h] = v;
      mx[h] = fmaxf(mx[h], v);
    }
    if (H == 4) ((float4*)wcsr)[e] = make_float4(a[0], a[1], a[2], a[3]);
    else wcsr[e] = a[0];
  }
#pragma unroll
  for (int off = 32; off; off >>= 1)
#pragma unroll
    for (int h = 0; h < H; h++) mx[h] = fmaxf(mx[h], __shfl_xor(mx[h], off));

  if (has0) {
#pragma unroll
    for (int h = 0; h < H; h++) { a0[h] = __expf(a0[h] - mx[h]); sm[h] += a0[h]; }
  }
  if (has1) {
#pragma unroll
    for (int h = 0; h < H; h++) { a1[h] = __expf(a1[h] - mx[h]); sm[h] += a1[h]; }
  }
  for (int e = rs + lane + 128; e < re; e += 64) {
    float a[H];
    if (H == 4) {
      float4 av = ((const float4*)wcsr)[e];
      a[0] = av.x; a[1] = av.y; a[2] = av.z; a[3] = av.w;
    } else a[0] = wcsr[e];
#pragma unroll
    for (int h = 0; h < H; h++) { a[h] = __expf(a[h] - mx[h]); sm[h] += a[h]; }
    if (H == 4) ((float4*)wcsr)[e] = make_float4(a[0], a[1], a[2], a[3]);
    else wcsr[e] = a[0];
  }
#pragma unroll
  for (int off = 32; off; off >>= 1)
#pragma unroll
    for (int h = 0; h < H; h++) sm[h] += __shfl_xor(sm[h], off);

  float inv[H];
#pragma unroll
  for (int h = 0; h < H; h++) inv[h] = 1.0f / (sm[h] + 1e-16f);

  if (has0) {
    if (H == 4) ((float4*)wcsr)[e0] =
        make_float4(a0[0] * inv[0], a0[1] * inv[1], a0[2] * inv[2], a0[3] * inv[3]);
    else wcsr[e0] = a0[0] * inv[0];
  }
  if (has1) {
    if (H == 4) ((float4*)wcsr)[e1] =
        make_float4(a1[0] * inv[0], a1[1] * inv[1], a1[2] * inv[2], a1[3] * inv[3]);
    else wcsr[e1] = a1[0] * inv[0];
  }
  for (int e = rs + lane + 128; e < re; e += 64) {
    if (H == 4) {
      float4 av = ((const float4*)wcsr)[e];
      ((float4*)wcsr)[e] =
          make_float4(av.x * inv[0], av.y * inv[1], av.z * inv[2], av.w * inv[3]);
    } else wcsr[e] = wcsr[e] * inv[0];
  }
}

// ---------------------------------------------------------------- aggregation
// one wave per node; lane owns 4 channels (bf16, 8B gathers); 8-deep unroll.
template <int H>
__global__ void k_agg(const int* __restrict__ rowst, const int* __restrict__ csrc,
                      const u16* __restrict__ hb, const float* __restrict__ wn,
                      const float* __restrict__ bias, float* __restrict__ out) {
  int n = blockIdx.x * 4 + (threadIdx.x >> 6);
  int lane = threadIdx.x & 63;
  if (n >= NN) return;
  int rs = rowst[n], re = rowst[n + 1];
  int head = (H == 4) ? (lane >> 4) : 0;
  const ushort4* h4 = (const ushort4*)hb;
  float4 acc0 = {0.f, 0.f, 0.f, 0.f}, acc1 = {0.f, 0.f, 0.f, 0.f};
  int e = rs;
  for (; e + 8 <= re; e += 8) {
    int s[8];
    float w[8];
    ushort4 v[8];
#pragma unroll
    for (int j = 0; j < 8; j++) s[j] = csrc[e + j];
#pragma unroll
    for (int j = 0; j < 8; j++) w[j] = wn[(e + j) * H + head];
#pragma unroll
    for (int j = 0; j < 8; j++) v[j] = h4[(size_t)s[j] * 64 + lane];
#pragma unroll
    for (int j = 0; j < 8; j++) {
      float wj = w[j];
      if (j & 1) {
        acc1.x = fmaf(wj, b2f(v[j].x), acc1.x);
        acc1.y = fmaf(wj, b2f(v[j].y), acc1.y);
        acc1.z = fmaf(wj, b2f(v[j].z), acc1.z);
        acc1.w = fmaf(wj, b2f(v[j].w), acc1.w);
      } else {
        acc0.x = fmaf(wj, b2f(v[j].x), acc0.x);
        acc0.y = fmaf(wj, b2f(v[j].y), acc0.y);
        acc0.z = fmaf(wj, b2f(v[j].z), acc0.z);
        acc0.w = fmaf(wj, b2f(v[j].w), acc0.w);
      }
    }
  }
  for (; e < re; e++) {
    int s = csrc[e];
    float w = wn[e * H + head];
    ushort4 v = h4[(size_t)s * 64 + lane];
    acc0.x = fmaf(w, b2f(v.x), acc0.x);
    acc0.y = fmaf(w, b2f(v.y), acc0.y);
    acc0.z = fmaf(w, b2f(v.z), acc0.z);
    acc0.w = fmaf(w, b2f(v.w), acc0.w);
  }
  float4 b4 = ((const float4*)bias)[lane];
  float4 r;
  r.x = acc0.x + acc1.x + b4.x;
  r.y = acc0.y + acc1.y + b4.y;
  r.z = acc0.z + acc1.z + b4.z;
  r.w = acc0.w + acc1.w + b4.w;
  ((float4*)out)[(size_t)n * 64 + lane] = r;
}

// ---------------------------------------------------------------- batch norm
__global__ void k_bnstats(const float* __restrict__ x, float* __restrict__ sums) {
  int t = threadIdx.x;
  int rows_per = (NN + gridDim.x - 1) / gridDim.x;
  int r0 = blockIdx.x * rows_per;
  int r1 = r0 + rows_per;
  if (r1 > NN) r1 = NN;
  float s = 0.f, ss = 0.f;
  for (int r = r0; r < r1; r++) {
    float v = x[(size_t)r * 256 + t];
    s += v;
    ss += v * v;
  }
  atomicAdd(&sums[t], s);
  atomicAdd(&sums[256 + t], ss);
}

template <int RELU, int BOUT>
__global__ void k_bnapply(const float* __restrict__ x, const float* __restrict__ sums,
                          const float* __restrict__ g, const float* __restrict__ be,
                          float* __restrict__ yf, u16* __restrict__ yb) {
  int i = blockIdx.x * 256 + threadIdx.x;
  int c = threadIdx.x;
  float m = sums[c] * (1.0f / NN);
  float v = sums[256 + c] * (1.0f / NN) - m * m;
  float val = (x[i] - m) * rsqrtf(v + 1e-5f) * g[c] + be[c];
  if (RELU) val = fmaxf(val, 0.f);
  if (BOUT) yb[i] = f2b(val);
  else yf[i] = val;
}

// ---------------------------------------------------------------- launch
extern "C" void kernel_launch(void* const* d_in, const int* in_sizes, int n_in,
                              void* d_out, int out_size, void* d_ws, size_t ws_size,
                              hipStream_t stream) {
  const float* x   = (const float*)d_in[0];
  const int*   ei  = (const int*)d_in[1];
  const float* W0  = (const float*)d_in[2];
  const float* as0 = (const float*)d_in[3];
  const float* ad0 = (const float*)d_in[4];
  const float* b0  = (const float*)d_in[5];
  const float* g0  = (const float*)d_in[6];
  const float* be0 = (const float*)d_in[7];
  const float* W1  = (const float*)d_in[8];
  const float* as1 = (const float*)d_in[9];
  const float* ad1 = (const float*)d_in[10];
  const float* b1  = (const float*)d_in[11];
  const float* g1  = (const float*)d_in[12];
  const float* be1 = (const float*)d_in[13];
  const float* W2  = (const float*)d_in[14];
  const float* as2 = (const float*)d_in[15];
  const float* ad2 = (const float*)d_in[16];
  const float* b2  = (const float*)d_in[17];
  const float* g2  = (const float*)d_in[18];
  const float* be2 = (const float*)d_in[19];
  float* out = (float*)d_out;

  // workspace layout
  u16* hb  = (u16*)d_ws;                  // NN*256 bf16
  u16* abf = hb + (size_t)NN * 256;       // NN*256 bf16 (gemm input)
  u16* Wt0 = abf + (size_t)NN * 256;      // 256*128
  u16* Wt1 = Wt0 + 256 * 128;             // 256*256
  u16* Wt2 = Wt1 + 256 * 256;             // 256*256
  float* asrc = (float*)(Wt2 + 256 * 256);  // NN*4
  float* adst = asrc + NN * 4;              // NN*4
  float* wcsr = adst + NN * 4;              // ET*4
  float* aggf = wcsr + (size_t)ET * 4;      // NN*256
  float* bns  = aggf + (size_t)NN * 256;    // 3*512
  int* cnt    = (int*)(bns + 1536);         // NN
  int* rowst  = cnt + NN;                   // NN+1
  int* cursor = rowst + NN + 1;             // NN
  int* csrc   = cursor + NN;                // ET

  // ---- CSR build + casts
  hipMemsetAsync(cnt, 0, NN * sizeof(int), stream);
  hipMemsetAsync(bns, 0, 1536 * sizeof(float), stream);
  k_count<<<(EE + 255) / 256, 256, 0, stream>>>(ei, cnt);
  k_scan<<<1, 1024, 0, stream>>>(cnt, rowst, cursor, csrc);
  k_fill<<<(EE + 255) / 256, 256, 0, stream>>>(ei, cursor, csrc);
  k_cast4<<<(NN * 128 / 4 + 255) / 256, 256, 0, stream>>>(x, abf, NN * 128 / 4);
  k_castW<<<(256 * 128 + 255) / 256, 256, 0, stream>>>(W0, Wt0, 128);
  k_castW<<<(256 * 256 + 255) / 256, 256, 0, stream>>>(W1, Wt1, 256);
  k_castW<<<(256 * 256 + 255) / 256, 256, 0, stream>>>(W2, Wt2, 256);

  dim3 ggrid((NN + 63) / 64, 4);
  int ngrid = (NN + 3) / 4;

  // ---- layer 0: GAT(128 -> 4x64) + BN + ReLU
  k_gemm<128><<<ggrid, 256, 0, stream>>>(abf, Wt0, hb);
  k_att<4><<<ngrid, 256, 0, stream>>>(hb, as0, ad0, asrc, adst);
  k_soft<4><<<ngrid, 256, 0, stream>>>(rowst, csrc, asrc, adst, wcsr);
  k_agg<4><<<ngrid, 256, 0, stream>>>(rowst, csrc, hb, wcsr, b0, aggf);
  k_bnstats<<<80, 256, 0, stream>>>(aggf, bns);
  k_bnapply<1, 1><<<NN, 256, 0, stream>>>(aggf, bns, g0, be0, nullptr, abf);

  // ---- layer 1: GAT(256 -> 4x64) + BN + ReLU
  k_gemm<256><<<ggrid, 256, 0, stream>>>(abf, Wt1, hb);
  k_att<4><<<ngrid, 256, 0, stream>>>(hb, as1, ad1, asrc, adst);
  k_soft<4><<<ngrid, 256, 0, stream>>>(rowst, csrc, asrc, adst, wcsr);
  k_agg<4><<<ngrid, 256, 0, stream>>>(rowst, csrc, hb, wcsr, b1, aggf);
  k_bnstats<<<80, 256, 0, stream>>>(aggf, bns + 512);
  k_bnapply<1, 1><<<NN, 256, 0, stream>>>(aggf, bns + 512, g1, be1, nullptr, abf);

  // ---- layer 2: GAT(256 -> 256, heads=1) + BN
  k_gemm<256><<<ggrid, 256, 0, stream>>>(abf, Wt2, hb);
  k_att<1><<<ngrid, 256, 0, stream>>>(hb, as2, ad2, asrc, adst);
  k_soft<1><<<ngrid, 256, 0, stream>>>(rowst, csrc, asrc, adst, wcsr);
  k_agg<1><<<ngrid, 256, 0, stream>>>(rowst, csrc, hb, wcsr, b2, aggf);
  k_bnstats<<<80, 256, 0, stream>>>(aggf, bns + 1024);
  k_bnapply<0, 0><<<NN, 256, 0, stream>>>(aggf, bns + 1024, g2, be2, out, nullptr);
}

// Round 5
// 372.248 us; speedup vs baseline: 1.6431x; 1.1217x over previous
//
#include <hip/hip_runtime.h>
#include <math.h>

#define NN 10000
#define EE 320000
#define ET (EE + NN)   // 330000 edges incl. self-loops

typedef __attribute__((ext_vector_type(8))) short short8;   // 8 x bf16 (4 VGPR)
typedef __attribute__((ext_vector_type(4))) float f32x4;
typedef unsigned short u16;

static __device__ __forceinline__ float b2f(u16 u) {
  return __uint_as_float(((unsigned)u) << 16);
}
static __device__ __forceinline__ u16 f2b(float f) {
  unsigned u = __float_as_uint(f);
  unsigned r = (u + 0x7FFFu + ((u >> 16) & 1u)) >> 16;  // RNE
  return (u16)r;
}

// ---------------------------------------------------------------- CSR build
__global__ void k_count(const int* __restrict__ ei, int* __restrict__ cnt) {
  int e = blockIdx.x * 256 + threadIdx.x;
  if (e < EE) atomicAdd(&cnt[ei[EE + e]], 1);
}

// single-block scan: 10 elems/thread + wave shfl scan + 16-wave LDS scan
__global__ __launch_bounds__(1024) void k_scan(const int* __restrict__ cnt,
                                               int* __restrict__ rowst,
                                               int* __restrict__ cursor,
                                               int* __restrict__ csrc) {
  __shared__ int ws[16];
  int tid = threadIdx.x, lane = tid & 63, wv = tid >> 6;
  int base = tid * 10;
  int v[10];
  int tot = 0;
#pragma unroll
  for (int i = 0; i < 10; i++) {
    int idx = base + i;
    v[i] = (idx < NN) ? (cnt[idx] + 1) : 0;
    tot += v[i];
  }
  int sc = tot;  // wave inclusive scan
#pragma unroll
  for (int off = 1; off < 64; off <<= 1) {
    int t = __shfl_up(sc, off);
    if (lane >= off) sc += t;
  }
  if (lane == 63) ws[wv] = sc;
  __syncthreads();
  if (wv == 0 && lane < 16) {
    int val = ws[lane];
    int s = val;
#pragma unroll
    for (int off = 1; off < 16; off <<= 1) {
      int t = __shfl_up(s, off);
      if (lane >= off) s += t;
    }
    ws[lane] = s - val;  // exclusive wave offset
  }
  __syncthreads();
  int run = ws[wv] + sc - tot;  // this thread's exclusive start
#pragma unroll
  for (int i = 0; i < 10; i++) {
    int idx = base + i;
    if (idx < NN) {
      rowst[idx] = run;
      csrc[run] = idx;        // self-loop at slot 0
      cursor[idx] = run + 1;  // real edges after it
      run += v[i];
    }
  }
  if (tid == 1023) rowst[NN] = run;  // == ET
}

__global__ void k_fill(const int* __restrict__ ei, int* __restrict__ cursor,
                       int* __restrict__ csrc) {
  int e = blockIdx.x * 256 + threadIdx.x;
  if (e < EE) {
    int d = ei[EE + e];
    int pos = atomicAdd(&cursor[d], 1);
    csrc[pos] = ei[e];
  }
}

// ---------------------------------------------------------------- all casts in one
// segment 0: x -> abf (float4 groups); 1..3: W0/W1/W2 -> Wt (transposed bf16)
__global__ void k_casts(const float* __restrict__ x, const float* __restrict__ W0,
                        const float* __restrict__ W1, const float* __restrict__ W2,
                        u16* __restrict__ abf, u16* __restrict__ Wt0,
                        u16* __restrict__ Wt1, u16* __restrict__ Wt2) {
  int t = blockIdx.x * 256 + threadIdx.x;
  const int NX4 = NN * 128 / 4;  // 320000
  if (t < NX4) {
    float4 f = ((const float4*)x)[t];
    ushort4 o;
    o.x = f2b(f.x); o.y = f2b(f.y); o.z = f2b(f.z); o.w = f2b(f.w);
    ((ushort4*)abf)[t] = o;
    return;
  }
  int u = t - NX4;
  if (u < 128 * 256) {
    int nI = u / 128, k = u - nI * 128;
    Wt0[u] = f2b(W0[(size_t)k * 256 + nI]);
    return;
  }
  u -= 128 * 256;
  if (u < 256 * 256) {
    int nI = u / 256, k = u - nI * 256;
    Wt1[u] = f2b(W1[(size_t)k * 256 + nI]);
    return;
  }
  u -= 256 * 256;
  if (u < 256 * 256) {
    int nI = u / 256, k = u - nI * 256;
    Wt2[u] = f2b(W2[(size_t)k * 256 + nI]);
  }
}

// ---------------------------------------------------------------- MFMA GEMM + att dots
// hb[M x 256] (bf16) = A[M x KK] (bf16) * Wt^T.  Epilogue: per-row attention
// dots over this block's 64 cols -> asrc/adst[row*4 + blockIdx.y].
// (H=4: y == head, full dot. H=1: 4 partials, summed in softagg.)
template <int KK>
__global__ __launch_bounds__(256) void k_gemm(const u16* __restrict__ A,
                                              const u16* __restrict__ Wt,
                                              const float* __restrict__ as,
                                              const float* __restrict__ ad,
                                              u16* __restrict__ hb,
                                              float* __restrict__ asrc,
                                              float* __restrict__ adst) {
  int wv = threadIdx.x >> 6, lane = threadIdx.x & 63;
  int row0 = blockIdx.x * 64 + wv * 16;
  int col0 = blockIdx.y * 64;
  int r = lane & 15, g = lane >> 4;
  f32x4 acc[4];
#pragma unroll
  for (int nt = 0; nt < 4; nt++) acc[nt] = (f32x4){0.f, 0.f, 0.f, 0.f};

  int ar = row0 + r;
  if (ar > NN - 1) ar = NN - 1;  // clamp (stores are guarded)
  const u16* Arow = A + (size_t)ar * KK + g * 8;

#pragma unroll
  for (int ks = 0; ks < KK / 32; ks++) {
    short8 af = *(const short8*)(Arow + ks * 32);
#pragma unroll
    for (int nt = 0; nt < 4; nt++) {
      short8 bf = *(const short8*)(Wt + (size_t)(col0 + nt * 16 + r) * KK + ks * 32 + g * 8);
      acc[nt] = __builtin_amdgcn_mfma_f32_16x16x32_bf16(af, bf, acc[nt], 0, 0, 0);
    }
  }
  // C/D: col = lane&15, row = (lane>>4)*4 + reg   [m89/m91]
#pragma unroll
  for (int nt = 0; nt < 4; nt++) {
    int col = col0 + nt * 16 + r;
#pragma unroll
    for (int q = 0; q < 4; q++) {
      int row = row0 + g * 4 + q;
      if (row < NN) hb[(size_t)row * 256 + col] = f2b(acc[nt][q]);
    }
  }
  // ---- attention-dot epilogue (f32 accuracy, no hb re-read)
  float asv[4], adv[4];
#pragma unroll
  for (int nt = 0; nt < 4; nt++) {
    asv[nt] = as[col0 + nt * 16 + r];
    adv[nt] = ad[col0 + nt * 16 + r];
  }
#pragma unroll
  for (int q = 0; q < 4; q++) {
    float ps = 0.f, pd = 0.f;
#pragma unroll
    for (int nt = 0; nt < 4; nt++) {
      ps = fmaf(acc[nt][q], asv[nt], ps);
      pd = fmaf(acc[nt][q], adv[nt], pd);
    }
#pragma unroll
    for (int off = 1; off < 16; off <<= 1) {  // reduce over r (16-lane group)
      ps += __shfl_xor(ps, off);
      pd += __shfl_xor(pd, off);
    }
    if (r == 0) {
      int row = row0 + g * 4 + q;
      if (row < NN) {
        asrc[row * 4 + blockIdx.y] = ps;
        adst[row * 4 + blockIdx.y] = pd;
      }
    }
  }
}

// ---------------------------------------------------------------- fused softmax+agg
// one wave per node. Phase A: segment softmax (logits in regs for first 128
// edges, weights+srcids parked in LDS). Phase B: 8-deep-unrolled bf16 row
// gathers, fma, normalize once at the end.  deg<=128 always here; cold
// recompute path keeps correctness beyond.
template <int H>
__global__ __launch_bounds__(256) void k_softagg(
    const int* __restrict__ rowst, const int* __restrict__ csrc,
    const float* __restrict__ asrc, const float* __restrict__ adst,
    const u16* __restrict__ hb, const float* __restrict__ bias,
    float* __restrict__ out) {
  __shared__ int lds_s[4][128];
  __shared__ float lds_w[4][128][H];
  int wv = threadIdx.x >> 6, lane = threadIdx.x & 63;
  int n = blockIdx.x * 4 + wv;  // NN % 4 == 0 -> always valid
  int rs = rowst[n], re = rowst[n + 1];

  float ad[H];
  {
    float4 t = ((const float4*)adst)[n];
    if (H == 4) { ad[0] = t.x; ad[1] = t.y; ad[2] = t.z; ad[3] = t.w; }
    else ad[0] = t.x + t.y + t.z + t.w;
  }
  float mx[H], sm[H];
#pragma unroll
  for (int h = 0; h < H; h++) { mx[h] = -1e30f; sm[h] = 0.f; }

  int e0 = rs + lane, e1 = e0 + 64;
  bool h0 = e0 < re, h1 = e1 < re;
  float a0[H], a1[H];

  if (h0) {
    int s = csrc[e0];
    lds_s[wv][lane] = s;
    float4 t = ((const float4*)asrc)[s];
    if (H == 4) { a0[0] = t.x; a0[1] = t.y; a0[2] = t.z; a0[3] = t.w; }
    else a0[0] = t.x + t.y + t.z + t.w;
#pragma unroll
    for (int h = 0; h < H; h++) {
      float v = a0[h] + ad[h];
      v = v > 0.f ? v : 0.2f * v;
      a0[h] = v;
      mx[h] = fmaxf(mx[h], v);
    }
  }
  if (h1) {
    int s = csrc[e1];
    lds_s[wv][64 + lane] = s;
    float4 t = ((const float4*)asrc)[s];
    if (H == 4) { a1[0] = t.x; a1[1] = t.y; a1[2] = t.z; a1[3] = t.w; }
    else a1[0] = t.x + t.y + t.z + t.w;
#pragma unroll
    for (int h = 0; h < H; h++) {
      float v = a1[h] + ad[h];
      v = v > 0.f ? v : 0.2f * v;
      a1[h] = v;
      mx[h] = fmaxf(mx[h], v);
    }
  }
  for (int e = rs + 128 + lane; e < re; e += 64) {  // cold: max only
    int s = csrc[e];
    float4 t = ((const float4*)asrc)[s];
    float a[H];
    if (H == 4) { a[0] = t.x; a[1] = t.y; a[2] = t.z; a[3] = t.w; }
    else a[0] = t.x + t.y + t.z + t.w;
#pragma unroll
    for (int h = 0; h < H; h++) {
      float v = a[h] + ad[h];
      v = v > 0.f ? v : 0.2f * v;
      mx[h] = fmaxf(mx[h], v);
    }
  }
#pragma unroll
  for (int off = 32; off; off >>= 1)
#pragma unroll
    for (int h = 0; h < H; h++) mx[h] = fmaxf(mx[h], __shfl_xor(mx[h], off));

  if (h0) {
#pragma unroll
    for (int h = 0; h < H; h++) {
      a0[h] = __expf(a0[h] - mx[h]);
      sm[h] += a0[h];
      lds_w[wv][lane][h] = a0[h];
    }
  }
  if (h1) {
#pragma unroll
    for (int h = 0; h < H; h++) {
      a1[h] = __expf(a1[h] - mx[h]);
      sm[h] += a1[h];
      lds_w[wv][64 + lane][h] = a1[h];
    }
  }
  for (int e = rs + 128 + lane; e < re; e += 64) {  // cold: exp+sum
    int s = csrc[e];
    float4 t = ((const float4*)asrc)[s];
    float a[H];
    if (H == 4) { a[0] = t.x; a[1] = t.y; a[2] = t.z; a[3] = t.w; }
    else a[0] = t.x + t.y + t.z + t.w;
#pragma unroll
    for (int h = 0; h < H; h++) {
      float v = a[h] + ad[h];
      v = v > 0.f ? v : 0.2f * v;
      sm[h] += __expf(v - mx[h]);
    }
  }
#pragma unroll
  for (int off = 32; off; off >>= 1)
#pragma unroll
    for (int h = 0; h < H; h++) sm[h] += __shfl_xor(sm[h], off);

  float inv[H];
#pragma unroll
  for (int h = 0; h < H; h++) inv[h] = 1.0f / (sm[h] + 1e-16f);

  __syncthreads();

  // ---- phase B: aggregation
  int hd = (H == 4) ? (lane >> 4) : 0;
  const ushort4* h4 = (const ushort4*)hb;
  float4 A0 = {0.f, 0.f, 0.f, 0.f}, A1 = {0.f, 0.f, 0.f, 0.f};
  int m = re - rs;
  if (m > 128) m = 128;
  int e = 0;
  for (; e + 8 <= m; e += 8) {
    int ss[8];
    float ww[8];
    ushort4 v[8];
#pragma unroll
    for (int j = 0; j < 8; j++) ss[j] = lds_s[wv][e + j];
#pragma unroll
    for (int j = 0; j < 8; j++) ww[j] = lds_w[wv][e + j][hd];
#pragma unroll
    for (int j = 0; j < 8; j++) v[j] = h4[(size_t)ss[j] * 64 + lane];
#pragma unroll
    for (int j = 0; j < 8; j++) {
      float w = ww[j];
      if (j & 1) {
        A1.x = fmaf(w, b2f(v[j].x), A1.x);
        A1.y = fmaf(w, b2f(v[j].y), A1.y);
        A1.z = fmaf(w, b2f(v[j].z), A1.z);
        A1.w = fmaf(w, b2f(v[j].w), A1.w);
      } else {
        A0.x = fmaf(w, b2f(v[j].x), A0.x);
        A0.y = fmaf(w, b2f(v[j].y), A0.y);
        A0.z = fmaf(w, b2f(v[j].z), A0.z);
        A0.w = fmaf(w, b2f(v[j].w), A0.w);
      }
    }
  }
  for (; e < m; e++) {
    int s = lds_s[wv][e];
    float w = lds_w[wv][e][hd];
    ushort4 v = h4[(size_t)s * 64 + lane];
    A0.x = fmaf(w, b2f(v.x), A0.x);
    A0.y = fmaf(w, b2f(v.y), A0.y);
    A0.z = fmaf(w, b2f(v.z), A0.z);
    A0.w = fmaf(w, b2f(v.w), A0.w);
  }
  for (int ee = rs + 128; ee < re; ee++) {  // cold: recompute w inline
    int s = csrc[ee];
    float4 t = ((const float4*)asrc)[s];
    float av, adh, mh;
    if (H == 4) {
      av = hd == 0 ? t.x : hd == 1 ? t.y : hd == 2 ? t.z : t.w;
      adh = hd == 0 ? ad[0] : hd == 1 ? ad[1] : hd == 2 ? ad[2] : ad[3];
      mh = hd == 0 ? mx[0] : hd == 1 ? mx[1] : hd == 2 ? mx[2] : mx[3];
    } else {
      av = t.x + t.y + t.z + t.w;
      adh = ad[0];
      mh = mx[0];
    }
    float vv = av + adh;
    vv = vv > 0.f ? vv : 0.2f * vv;
    float w = __expf(vv - mh);
    ushort4 v = h4[(size_t)s * 64 + lane];
    A0.x = fmaf(w, b2f(v.x), A0.x);
    A0.y = fmaf(w, b2f(v.y), A0.y);
    A0.z = fmaf(w, b2f(v.z), A0.z);
    A0.w = fmaf(w, b2f(v.w), A0.w);
  }
  float invh;
  if (H == 4)
    invh = hd == 0 ? inv[0] : hd == 1 ? inv[1] : hd == 2 ? inv[2] : inv[3];
  else
    invh = inv[0];
  float4 b4 = ((const float4*)bias)[lane];
  float4 r4;
  r4.x = (A0.x + A1.x) * invh + b4.x;
  r4.y = (A0.y + A1.y) * invh + b4.y;
  r4.z = (A0.z + A1.z) * invh + b4.z;
  r4.w = (A0.w + A1.w) * invh + b4.w;
  ((float4*)out)[(size_t)n * 64 + lane] = r4;
}

// ---------------------------------------------------------------- batch norm
__global__ void k_bnstats(const float* __restrict__ x, float* __restrict__ sums) {
  int t = threadIdx.x;
  int rows_per = (NN + gridDim.x - 1) / gridDim.x;
  int r0 = blockIdx.x * rows_per;
  int r1 = r0 + rows_per;
  if (r1 > NN) r1 = NN;
  float s = 0.f, ss = 0.f;
  for (int r = r0; r < r1; r++) {
    float v = x[(size_t)r * 256 + t];
    s += v;
    ss += v * v;
  }
  atomicAdd(&sums[t], s);
  atomicAdd(&sums[256 + t], ss);
}

template <int RELU, int BOUT>
__global__ void k_bnapply(const float* __restrict__ x, const float* __restrict__ sums,
                          const float* __restrict__ g, const float* __restrict__ be,
                          float* __restrict__ yf, u16* __restrict__ yb) {
  int i = blockIdx.x * 256 + threadIdx.x;  // float4 index, total NN*64
  int c = i & 63;
  float4 s4 = ((const float4*)sums)[c];
  float4 q4 = ((const float4*)sums)[64 + c];
  float4 g4 = ((const float4*)g)[c];
  float4 b4 = ((const float4*)be)[c];
  float4 xv = ((const float4*)x)[i];
  float4 r;
  {
    float m = s4.x * (1.0f / NN), v = q4.x * (1.0f / NN) - m * m;
    r.x = (xv.x - m) * rsqrtf(v + 1e-5f) * g4.x + b4.x;
    m = s4.y * (1.0f / NN); v = q4.y * (1.0f / NN) - m * m;
    r.y = (xv.y - m) * rsqrtf(v + 1e-5f) * g4.y + b4.y;
    m = s4.z * (1.0f / NN); v = q4.z * (1.0f / NN) - m * m;
    r.z = (xv.z - m) * rsqrtf(v + 1e-5f) * g4.z + b4.z;
    m = s4.w * (1.0f / NN); v = q4.w * (1.0f / NN) - m * m;
    r.w = (xv.w - m) * rsqrtf(v + 1e-5f) * g4.w + b4.w;
  }
  if (RELU) {
    r.x = fmaxf(r.x, 0.f); r.y = fmaxf(r.y, 0.f);
    r.z = fmaxf(r.z, 0.f); r.w = fmaxf(r.w, 0.f);
  }
  if (BOUT) {
    ushort4 o;
    o.x = f2b(r.x); o.y = f2b(r.y); o.z = f2b(r.z); o.w = f2b(r.w);
    ((ushort4*)yb)[i] = o;
  } else {
    ((float4*)yf)[i] = r;
  }
}

// ---------------------------------------------------------------- launch
extern "C" void kernel_launch(void* const* d_in, const int* in_sizes, int n_in,
                              void* d_out, int out_size, void* d_ws, size_t ws_size,
                              hipStream_t stream) {
  const float* x   = (const float*)d_in[0];
  const int*   ei  = (const int*)d_in[1];
  const float* W0  = (const float*)d_in[2];
  const float* as0 = (const float*)d_in[3];
  const float* ad0 = (const float*)d_in[4];
  const float* b0  = (const float*)d_in[5];
  const float* g0  = (const float*)d_in[6];
  const float* be0 = (const float*)d_in[7];
  const float* W1  = (const float*)d_in[8];
  const float* as1 = (const float*)d_in[9];
  const float* ad1 = (const float*)d_in[10];
  const float* b1  = (const float*)d_in[11];
  const float* g1  = (const float*)d_in[12];
  const float* be1 = (const float*)d_in[13];
  const float* W2  = (const float*)d_in[14];
  const float* as2 = (const float*)d_in[15];
  const float* ad2 = (const float*)d_in[16];
  const float* b2  = (const float*)d_in[17];
  const float* g2  = (const float*)d_in[18];
  const float* be2 = (const float*)d_in[19];
  float* out = (float*)d_out;

  // workspace layout
  u16* hb  = (u16*)d_ws;                    // NN*256 bf16
  u16* abf = hb + (size_t)NN * 256;         // NN*256 bf16 (gemm input)
  u16* Wt0 = abf + (size_t)NN * 256;        // 256*128
  u16* Wt1 = Wt0 + 256 * 128;               // 256*256
  u16* Wt2 = Wt1 + 256 * 256;               // 256*256
  float* asrc = (float*)(Wt2 + 256 * 256);  // NN*4
  float* adst = asrc + NN * 4;              // NN*4
  float* aggf = adst + NN * 4;              // NN*256 f32
  float* bns  = aggf + (size_t)NN * 256;    // 3*512
  int* cnt    = (int*)(bns + 1536);         // NN   (adjacent to bns -> one memset)
  int* rowst  = cnt + NN;                   // NN+1
  int* cursor = rowst + NN + 1;             // NN
  int* csrc   = cursor + NN;                // ET

  // ---- CSR build + casts (5 dispatches)
  hipMemsetAsync(bns, 0, (1536 + NN) * sizeof(int), stream);
  k_count<<<(EE + 255) / 256, 256, 0, stream>>>(ei, cnt);
  k_scan<<<1, 1024, 0, stream>>>(cnt, rowst, cursor, csrc);
  k_fill<<<(EE + 255) / 256, 256, 0, stream>>>(ei, cursor, csrc);
  {
    int total = NN * 128 / 4 + 128 * 256 + 256 * 256 + 256 * 256;
    k_casts<<<(total + 255) / 256, 256, 0, stream>>>(x, W0, W1, W2, abf, Wt0, Wt1, Wt2);
  }

  dim3 ggrid((NN + 63) / 64, 4);

  // ---- layer 0
  k_gemm<128><<<ggrid, 256, 0, stream>>>(abf, Wt0, as0, ad0, hb, asrc, adst);
  k_softagg<4><<<NN / 4, 256, 0, stream>>>(rowst, csrc, asrc, adst, hb, b0, aggf);
  k_bnstats<<<80, 256, 0, stream>>>(aggf, bns);
  k_bnapply<1, 1><<<NN / 4, 256, 0, stream>>>(aggf, bns, g0, be0, nullptr, abf);

  // ---- layer 1
  k_gemm<256><<<ggrid, 256, 0, stream>>>(abf, Wt1, as1, ad1, hb, asrc, adst);
  k_softagg<4><<<NN / 4, 256, 0, stream>>>(rowst, csrc, asrc, adst, hb, b1, aggf);
  k_bnstats<<<80, 256, 0, stream>>>(aggf, bns + 512);
  k_bnapply<1, 1><<<NN / 4, 256, 0, stream>>>(aggf, bns + 512, g1, be1, nullptr, abf);

  // ---- layer 2 (H=1; gemm wrote 4 col-partials per dot, softagg sums them)
  k_gemm<256><<<ggrid, 256, 0, stream>>>(abf, Wt2, as2, ad2, hb, asrc, adst);
  k_softagg<1><<<NN / 4, 256, 0, stream>>>(rowst, csrc, asrc, adst, hb, b2, aggf);
  k_bnstats<<<80, 256, 0, stream>>>(aggf, bns + 1024);
  k_bnapply<0, 0><<<NN / 4, 256, 0, stream>>>(aggf, bns + 1024, g2, be2, out, nullptr);
}

// Round 6
// 337.977 us; speedup vs baseline: 1.8097x; 1.1014x over previous
//
#include <hip/hip_runtime.h>
#include <math.h>

#define NN 10000
#define EE 320000
#define ET (EE + NN)   // 330000 edges incl. self-loops

typedef __attribute__((ext_vector_type(8))) short short8;   // 8 x bf16 (4 VGPR)
typedef __attribute__((ext_vector_type(4))) float f32x4;
typedef unsigned short u16;

static __device__ __forceinline__ float b2f(u16 u) {
  return __uint_as_float(((unsigned)u) << 16);
}
static __device__ __forceinline__ u16 f2b(float f) {
  unsigned u = __float_as_uint(f);
  unsigned r = (u + 0x7FFFu + ((u >> 16) & 1u)) >> 16;  // RNE
  return (u16)r;
}

// ---------------------------------------------------------------- CSR build
__global__ void k_count(const int* __restrict__ ei, int* __restrict__ cnt) {
  int e = blockIdx.x * 256 + threadIdx.x;
  if (e < EE) atomicAdd(&cnt[ei[EE + e]], 1);
}

__global__ __launch_bounds__(1024) void k_scan(const int* __restrict__ cnt,
                                               int* __restrict__ rowst,
                                               int* __restrict__ cursor,
                                               int* __restrict__ csrc) {
  __shared__ int ws[16];
  int tid = threadIdx.x, lane = tid & 63, wv = tid >> 6;
  int base = tid * 10;
  int v[10];
  int tot = 0;
#pragma unroll
  for (int i = 0; i < 10; i++) {
    int idx = base + i;
    v[i] = (idx < NN) ? (cnt[idx] + 1) : 0;
    tot += v[i];
  }
  int sc = tot;
#pragma unroll
  for (int off = 1; off < 64; off <<= 1) {
    int t = __shfl_up(sc, off);
    if (lane >= off) sc += t;
  }
  if (lane == 63) ws[wv] = sc;
  __syncthreads();
  if (wv == 0 && lane < 16) {
    int val = ws[lane];
    int s = val;
#pragma unroll
    for (int off = 1; off < 16; off <<= 1) {
      int t = __shfl_up(s, off);
      if (lane >= off) s += t;
    }
    ws[lane] = s - val;
  }
  __syncthreads();
  int run = ws[wv] + sc - tot;
#pragma unroll
  for (int i = 0; i < 10; i++) {
    int idx = base + i;
    if (idx < NN) {
      rowst[idx] = run;
      csrc[run] = idx;        // self-loop at slot 0
      cursor[idx] = run + 1;
      run += v[i];
    }
  }
  if (tid == 1023) rowst[NN] = run;
}

__global__ void k_fill(const int* __restrict__ ei, int* __restrict__ cursor,
                       int* __restrict__ csrc) {
  int e = blockIdx.x * 256 + threadIdx.x;
  if (e < EE) {
    int d = ei[EE + e];
    int pos = atomicAdd(&cursor[d], 1);
    csrc[pos] = ei[e];
  }
}

// ---------------------------------------------------------------- casts
__global__ void k_casts(const float* __restrict__ x, const float* __restrict__ W0,
                        const float* __restrict__ W1, const float* __restrict__ W2,
                        u16* __restrict__ abf, u16* __restrict__ Wt0,
                        u16* __restrict__ Wt1, u16* __restrict__ Wt2) {
  int t = blockIdx.x * 256 + threadIdx.x;
  const int NX4 = NN * 128 / 4;  // 320000
  if (t < NX4) {
    float4 f = ((const float4*)x)[t];
    ushort4 o;
    o.x = f2b(f.x); o.y = f2b(f.y); o.z = f2b(f.z); o.w = f2b(f.w);
    ((ushort4*)abf)[t] = o;
    return;
  }
  int u = t - NX4;
  if (u < 128 * 256) {
    int nI = u / 128, k = u - nI * 128;
    Wt0[u] = f2b(W0[(size_t)k * 256 + nI]);
    return;
  }
  u -= 128 * 256;
  if (u < 256 * 256) {
    int nI = u / 256, k = u - nI * 256;
    Wt1[u] = f2b(W1[(size_t)k * 256 + nI]);
    return;
  }
  u -= 256 * 256;
  if (u < 256 * 256) {
    int nI = u / 256, k = u - nI * 256;
    Wt2[u] = f2b(W2[(size_t)k * 256 + nI]);
  }
}

// ---------------------------------------------------------------- MFMA GEMM (+BN in, +att dots out)
// Block = 64 rows x 128 cols, 4 waves (wave = 16 rows x 128 cols, acc 8xf32x4).
// grid (157, 2).  BN=1: A read from f32 prev-layer output, BN+ReLU applied
// inline (stats reduced from 32 bucket-partials at block start). Epilogue
// computes attention dots from the f32 accumulators.
// Slot layout asrc/adst[row*4 + slot]: H=4 -> slot = head; H=1 -> slots
// {2y} hold col-half partials, {2y+1} = 0 (softagg sums all 4 slots).
template <int KK, int BN>
__global__ __launch_bounds__(256) void k_gemm(
    const u16* __restrict__ A, const float* __restrict__ Af,
    const float* __restrict__ bkt, const float* __restrict__ gam,
    const float* __restrict__ bet, const u16* __restrict__ Wt,
    const float* __restrict__ as, const float* __restrict__ ad,
    u16* __restrict__ hb, float* __restrict__ asrc, float* __restrict__ adst,
    int H) {
  __shared__ float2 bnp[256];  // (scale, shift) per input channel
  if (BN) {
    int t = threadIdx.x;
    float s = 0.f, q = 0.f;
#pragma unroll 8
    for (int b = 0; b < 32; b++) {
      s += bkt[b * 512 + t];
      q += bkt[b * 512 + 256 + t];
    }
    float m = s * (1.0f / NN);
    float v = q * (1.0f / NN) - m * m;
    float rs = rsqrtf(v + 1e-5f) * gam[t];
    bnp[t] = make_float2(rs, bet[t] - m * rs);
    __syncthreads();
  }
  int wv = threadIdx.x >> 6, lane = threadIdx.x & 63;
  int row0 = blockIdx.x * 64 + wv * 16;
  int col0 = blockIdx.y * 128;
  int r = lane & 15, g = lane >> 4;
  f32x4 acc[8];
#pragma unroll
  for (int nt = 0; nt < 8; nt++) acc[nt] = (f32x4){0.f, 0.f, 0.f, 0.f};

  int ar = row0 + r;
  if (ar > NN - 1) ar = NN - 1;  // clamp (stores guarded)

#pragma unroll
  for (int ks = 0; ks < KK / 32; ks++) {
    short8 af;
    if (BN == 0) {
      af = *(const short8*)(A + (size_t)ar * KK + ks * 32 + g * 8);
    } else {
      int c0 = ks * 32 + g * 8;
      float4 a0 = ((const float4*)Af)[(size_t)ar * (KK / 4) + c0 / 4];
      float4 a1 = ((const float4*)Af)[(size_t)ar * (KK / 4) + c0 / 4 + 1];
      float vv[8] = {a0.x, a0.y, a0.z, a0.w, a1.x, a1.y, a1.z, a1.w};
#pragma unroll
      for (int j = 0; j < 8; j++) {
        float2 p = bnp[c0 + j];
        float t = fmaxf(fmaf(vv[j], p.x, p.y), 0.f);
        af[j] = (short)f2b(t);
      }
    }
#pragma unroll
    for (int nt = 0; nt < 8; nt++) {
      short8 bf = *(const short8*)(Wt + (size_t)(col0 + nt * 16 + r) * KK + ks * 32 + g * 8);
      acc[nt] = __builtin_amdgcn_mfma_f32_16x16x32_bf16(af, bf, acc[nt], 0, 0, 0);
    }
  }
  // C/D: col = lane&15, row = (lane>>4)*4 + reg   [m89/m91]
#pragma unroll
  for (int nt = 0; nt < 8; nt++) {
    int col = col0 + nt * 16 + r;
#pragma unroll
    for (int q = 0; q < 4; q++) {
      int row = row0 + g * 4 + q;
      if (row < NN) hb[(size_t)row * 256 + col] = f2b(acc[nt][q]);
    }
  }
  // ---- attention-dot epilogue
  float asv[8], adv[8];
#pragma unroll
  for (int nt = 0; nt < 8; nt++) {
    asv[nt] = as[col0 + nt * 16 + r];
    adv[nt] = ad[col0 + nt * 16 + r];
  }
#pragma unroll
  for (int q = 0; q < 4; q++) {
    int row = row0 + g * 4 + q;
    if (H == 4) {
#pragma unroll
      for (int hh = 0; hh < 2; hh++) {
        float ps = 0.f, pd = 0.f;
#pragma unroll
        for (int k = 0; k < 4; k++) {
          ps = fmaf(acc[hh * 4 + k][q], asv[hh * 4 + k], ps);
          pd = fmaf(acc[hh * 4 + k][q], adv[hh * 4 + k], pd);
        }
#pragma unroll
        for (int off = 1; off < 16; off <<= 1) {
          ps += __shfl_xor(ps, off);
          pd += __shfl_xor(pd, off);
        }
        if (r == 0 && row < NN) {
          int slot = 2 * blockIdx.y + hh;
          asrc[row * 4 + slot] = ps;
          adst[row * 4 + slot] = pd;
        }
      }
    } else {
      float ps = 0.f, pd = 0.f;
#pragma unroll
      for (int nt = 0; nt < 8; nt++) {
        ps = fmaf(acc[nt][q], asv[nt], ps);
        pd = fmaf(acc[nt][q], adv[nt], pd);
      }
#pragma unroll
      for (int off = 1; off < 16; off <<= 1) {
        ps += __shfl_xor(ps, off);
        pd += __shfl_xor(pd, off);
      }
      if (r == 0 && row < NN) {
        int slot = 2 * blockIdx.y;
        asrc[row * 4 + slot] = ps;
        asrc[row * 4 + slot + 1] = 0.f;
        adst[row * 4 + slot] = pd;
        adst[row * 4 + slot + 1] = 0.f;
      }
    }
  }
}

// ---------------------------------------------------------------- fused softmax+agg (+BN partials)
template <int H>
__global__ __launch_bounds__(256) void k_softagg(
    const int* __restrict__ rowst, const int* __restrict__ csrc,
    const float* __restrict__ asrc, const float* __restrict__ adst,
    const u16* __restrict__ hb, const float* __restrict__ bias,
    float* __restrict__ out, float* __restrict__ bkt) {
  __shared__ int lds_s[4][128];
  __shared__ float lds_w[4][128][H];
  __shared__ float4 lds_rv[4][64];
  __shared__ float4 lds_rq[4][64];
  int wv = threadIdx.x >> 6, lane = threadIdx.x & 63;
  int n = blockIdx.x * 4 + wv;  // NN % 4 == 0
  int rs = rowst[n], re = rowst[n + 1];

  float ad[H];
  {
    float4 t = ((const float4*)adst)[n];
    if (H == 4) { ad[0] = t.x; ad[1] = t.y; ad[2] = t.z; ad[3] = t.w; }
    else ad[0] = t.x + t.y + t.z + t.w;
  }
  float mx[H], sm[H];
#pragma unroll
  for (int h = 0; h < H; h++) { mx[h] = -1e30f; sm[h] = 0.f; }

  int e0 = rs + lane, e1 = e0 + 64;
  bool h0 = e0 < re, h1 = e1 < re;
  float a0[H], a1[H];

  if (h0) {
    int s = csrc[e0];
    lds_s[wv][lane] = s;
    float4 t = ((const float4*)asrc)[s];
    if (H == 4) { a0[0] = t.x; a0[1] = t.y; a0[2] = t.z; a0[3] = t.w; }
    else a0[0] = t.x + t.y + t.z + t.w;
#pragma unroll
    for (int h = 0; h < H; h++) {
      float v = a0[h] + ad[h];
      v = v > 0.f ? v : 0.2f * v;
      a0[h] = v;
      mx[h] = fmaxf(mx[h], v);
    }
  }
  if (h1) {
    int s = csrc[e1];
    lds_s[wv][64 + lane] = s;
    float4 t = ((const float4*)asrc)[s];
    if (H == 4) { a1[0] = t.x; a1[1] = t.y; a1[2] = t.z; a1[3] = t.w; }
    else a1[0] = t.x + t.y + t.z + t.w;
#pragma unroll
    for (int h = 0; h < H; h++) {
      float v = a1[h] + ad[h];
      v = v > 0.f ? v : 0.2f * v;
      a1[h] = v;
      mx[h] = fmaxf(mx[h], v);
    }
  }
  for (int e = rs + 128 + lane; e < re; e += 64) {  // cold path (deg>128)
    int s = csrc[e];
    float4 t = ((const float4*)asrc)[s];
    float a[H];
    if (H == 4) { a[0] = t.x; a[1] = t.y; a[2] = t.z; a[3] = t.w; }
    else a[0] = t.x + t.y + t.z + t.w;
#pragma unroll
    for (int h = 0; h < H; h++) {
      float v = a[h] + ad[h];
      v = v > 0.f ? v : 0.2f * v;
      mx[h] = fmaxf(mx[h], v);
    }
  }
#pragma unroll
  for (int off = 32; off; off >>= 1)
#pragma unroll
    for (int h = 0; h < H; h++) mx[h] = fmaxf(mx[h], __shfl_xor(mx[h], off));

  if (h0) {
#pragma unroll
    for (int h = 0; h < H; h++) {
      a0[h] = __expf(a0[h] - mx[h]);
      sm[h] += a0[h];
      lds_w[wv][lane][h] = a0[h];
    }
  }
  if (h1) {
#pragma unroll
    for (int h = 0; h < H; h++) {
      a1[h] = __expf(a1[h] - mx[h]);
      sm[h] += a1[h];
      lds_w[wv][64 + lane][h] = a1[h];
    }
  }
  for (int e = rs + 128 + lane; e < re; e += 64) {
    int s = csrc[e];
    float4 t = ((const float4*)asrc)[s];
    float a[H];
    if (H == 4) { a[0] = t.x; a[1] = t.y; a[2] = t.z; a[3] = t.w; }
    else a[0] = t.x + t.y + t.z + t.w;
#pragma unroll
    for (int h = 0; h < H; h++) {
      float v = a[h] + ad[h];
      v = v > 0.f ? v : 0.2f * v;
      sm[h] += __expf(v - mx[h]);
    }
  }
#pragma unroll
  for (int off = 32; off; off >>= 1)
#pragma unroll
    for (int h = 0; h < H; h++) sm[h] += __shfl_xor(sm[h], off);

  float inv[H];
#pragma unroll
  for (int h = 0; h < H; h++) inv[h] = 1.0f / (sm[h] + 1e-16f);

  __syncthreads();

  // ---- phase B: aggregation
  int hd = (H == 4) ? (lane >> 4) : 0;
  const ushort4* h4 = (const ushort4*)hb;
  float4 A0 = {0.f, 0.f, 0.f, 0.f}, A1 = {0.f, 0.f, 0.f, 0.f};
  int m = re - rs;
  if (m > 128) m = 128;
  int e = 0;
  for (; e + 8 <= m; e += 8) {
    int ss[8];
    float ww[8];
    ushort4 v[8];
#pragma unroll
    for (int j = 0; j < 8; j++) ss[j] = lds_s[wv][e + j];
#pragma unroll
    for (int j = 0; j < 8; j++) ww[j] = lds_w[wv][e + j][hd];
#pragma unroll
    for (int j = 0; j < 8; j++) v[j] = h4[(size_t)ss[j] * 64 + lane];
#pragma unroll
    for (int j = 0; j < 8; j++) {
      float w = ww[j];
      if (j & 1) {
        A1.x = fmaf(w, b2f(v[j].x), A1.x);
        A1.y = fmaf(w, b2f(v[j].y), A1.y);
        A1.z = fmaf(w, b2f(v[j].z), A1.z);
        A1.w = fmaf(w, b2f(v[j].w), A1.w);
      } else {
        A0.x = fmaf(w, b2f(v[j].x), A0.x);
        A0.y = fmaf(w, b2f(v[j].y), A0.y);
        A0.z = fmaf(w, b2f(v[j].z), A0.z);
        A0.w = fmaf(w, b2f(v[j].w), A0.w);
      }
    }
  }
  for (; e < m; e++) {
    int s = lds_s[wv][e];
    float w = lds_w[wv][e][hd];
    ushort4 v = h4[(size_t)s * 64 + lane];
    A0.x = fmaf(w, b2f(v.x), A0.x);
    A0.y = fmaf(w, b2f(v.y), A0.y);
    A0.z = fmaf(w, b2f(v.z), A0.z);
    A0.w = fmaf(w, b2f(v.w), A0.w);
  }
  for (int ee = rs + 128; ee < re; ee++) {  // cold path
    int s = csrc[ee];
    float4 t = ((const float4*)asrc)[s];
    float av, adh, mh;
    if (H == 4) {
      av = hd == 0 ? t.x : hd == 1 ? t.y : hd == 2 ? t.z : t.w;
      adh = hd == 0 ? ad[0] : hd == 1 ? ad[1] : hd == 2 ? ad[2] : ad[3];
      mh = hd == 0 ? mx[0] : hd == 1 ? mx[1] : hd == 2 ? mx[2] : mx[3];
    } else {
      av = t.x + t.y + t.z + t.w;
      adh = ad[0];
      mh = mx[0];
    }
    float vv = av + adh;
    vv = vv > 0.f ? vv : 0.2f * vv;
    float w = __expf(vv - mh);
    ushort4 v = h4[(size_t)s * 64 + lane];
    A0.x = fmaf(w, b2f(v.x), A0.x);
    A0.y = fmaf(w, b2f(v.y), A0.y);
    A0.z = fmaf(w, b2f(v.z), A0.z);
    A0.w = fmaf(w, b2f(v.w), A0.w);
  }
  float invh;
  if (H == 4)
    invh = hd == 0 ? inv[0] : hd == 1 ? inv[1] : hd == 2 ? inv[2] : inv[3];
  else
    invh = inv[0];
  float4 b4 = ((const float4*)bias)[lane];
  float4 r4;
  r4.x = (A0.x + A1.x) * invh + b4.x;
  r4.y = (A0.y + A1.y) * invh + b4.y;
  r4.z = (A0.z + A1.z) * invh + b4.z;
  r4.w = (A0.w + A1.w) * invh + b4.w;
  ((float4*)out)[(size_t)n * 64 + lane] = r4;

  // ---- BN partial epilogue: block-reduce 4 nodes, 512 atomics into bucket
  float4 q4;
  q4.x = r4.x * r4.x; q4.y = r4.y * r4.y;
  q4.z = r4.z * r4.z; q4.w = r4.w * r4.w;
  lds_rv[wv][lane] = r4;
  lds_rq[wv][lane] = q4;
  __syncthreads();
  if (wv == 0) {
    float4 sv = lds_rv[0][lane], sq = lds_rq[0][lane];
#pragma unroll
    for (int w = 1; w < 4; w++) {
      float4 tv = lds_rv[w][lane], tq = lds_rq[w][lane];
      sv.x += tv.x; sv.y += tv.y; sv.z += tv.z; sv.w += tv.w;
      sq.x += tq.x; sq.y += tq.y; sq.z += tq.z; sq.w += tq.w;
    }
    float* pv = bkt + (blockIdx.x & 31) * 512 + lane * 4;
    atomicAdd(pv + 0, sv.x); atomicAdd(pv + 1, sv.y);
    atomicAdd(pv + 2, sv.z); atomicAdd(pv + 3, sv.w);
    float* pq = pv + 256;
    atomicAdd(pq + 0, sq.x); atomicAdd(pq + 1, sq.y);
    atomicAdd(pq + 2, sq.z); atomicAdd(pq + 3, sq.w);
  }
}

// ---------------------------------------------------------------- final BN
__global__ void k_bnred(const float* __restrict__ bkt, const float* __restrict__ g,
                        const float* __restrict__ be, float* __restrict__ rsg,
                        float* __restrict__ sh) {
  int t = threadIdx.x;  // 256
  float s = 0.f, q = 0.f;
#pragma unroll 8
  for (int b = 0; b < 32; b++) {
    s += bkt[b * 512 + t];
    q += bkt[b * 512 + 256 + t];
  }
  float m = s * (1.0f / NN);
  float v = q * (1.0f / NN) - m * m;
  float rs = rsqrtf(v + 1e-5f) * g[t];
  rsg[t] = rs;
  sh[t] = be[t] - m * rs;
}

__global__ void k_bnout(const float* __restrict__ x, const float* __restrict__ rsg,
                        const float* __restrict__ sh, float* __restrict__ y) {
  int i = blockIdx.x * 256 + threadIdx.x;  // float4 index over NN*64
  int c = i & 63;
  float4 rs4 = ((const float4*)rsg)[c];
  float4 sh4 = ((const float4*)sh)[c];
  float4 xv = ((const float4*)x)[i];
  float4 r;
  r.x = fmaf(xv.x, rs4.x, sh4.x);
  r.y = fmaf(xv.y, rs4.y, sh4.y);
  r.z = fmaf(xv.z, rs4.z, sh4.z);
  r.w = fmaf(xv.w, rs4.w, sh4.w);
  ((float4*)y)[i] = r;
}

// ---------------------------------------------------------------- launch
extern "C" void kernel_launch(void* const* d_in, const int* in_sizes, int n_in,
                              void* d_out, int out_size, void* d_ws, size_t ws_size,
                              hipStream_t stream) {
  const float* x   = (const float*)d_in[0];
  const int*   ei  = (const int*)d_in[1];
  const float* W0  = (const float*)d_in[2];
  const float* as0 = (const float*)d_in[3];
  const float* ad0 = (const float*)d_in[4];
  const float* b0  = (const float*)d_in[5];
  const float* g0  = (const float*)d_in[6];
  const float* be0 = (const float*)d_in[7];
  const float* W1  = (const float*)d_in[8];
  const float* as1 = (const float*)d_in[9];
  const float* ad1 = (const float*)d_in[10];
  const float* b1  = (const float*)d_in[11];
  const float* g1  = (const float*)d_in[12];
  const float* be1 = (const float*)d_in[13];
  const float* W2  = (const float*)d_in[14];
  const float* as2 = (const float*)d_in[15];
  const float* ad2 = (const float*)d_in[16];
  const float* b2  = (const float*)d_in[17];
  const float* g2  = (const float*)d_in[18];
  const float* be2 = (const float*)d_in[19];
  float* out = (float*)d_out;

  // workspace layout
  u16* hb  = (u16*)d_ws;                    // NN*256 bf16
  u16* abf = hb + (size_t)NN * 256;         // NN*128 bf16 (layer-0 input)
  u16* Wt0 = abf + (size_t)NN * 128;        // 256*128
  u16* Wt1 = Wt0 + 256 * 128;               // 256*256
  u16* Wt2 = Wt1 + 256 * 256;               // 256*256
  float* asrc = (float*)(Wt2 + 256 * 256);  // NN*4
  float* adst = asrc + NN * 4;              // NN*4
  float* aggf = adst + NN * 4;              // NN*256 f32
  float* bkt  = aggf + (size_t)NN * 256;    // 3 * 32 * 512
  float* rsg2 = bkt + 3 * 32 * 512;         // 256
  float* sh2  = rsg2 + 256;                 // 256
  int* cnt    = (int*)(sh2 + 256);          // NN (adjacent to bkt block -> one memset)
  int* rowst  = cnt + NN;                   // NN+1
  int* cursor = rowst + NN + 1;             // NN
  int* csrc   = cursor + NN;                // ET

  // ---- one memset covers buckets + rsg/sh + cnt
  hipMemsetAsync(bkt, 0, (3 * 32 * 512 + 512 + NN) * sizeof(float), stream);
  k_count<<<(EE + 255) / 256, 256, 0, stream>>>(ei, cnt);
  k_scan<<<1, 1024, 0, stream>>>(cnt, rowst, cursor, csrc);
  k_fill<<<(EE + 255) / 256, 256, 0, stream>>>(ei, cursor, csrc);
  {
    int total = NN * 128 / 4 + 128 * 256 + 256 * 256 + 256 * 256;
    k_casts<<<(total + 255) / 256, 256, 0, stream>>>(x, W0, W1, W2, abf, Wt0, Wt1, Wt2);
  }

  dim3 ggrid((NN + 63) / 64, 2);

  // ---- layer 0 (no input BN)
  k_gemm<128, 0><<<ggrid, 256, 0, stream>>>(abf, nullptr, nullptr, nullptr, nullptr,
                                            Wt0, as0, ad0, hb, asrc, adst, 4);
  k_softagg<4><<<NN / 4, 256, 0, stream>>>(rowst, csrc, asrc, adst, hb, b0, aggf, bkt);

  // ---- layer 1 (BN0+ReLU fused into A-load)
  k_gemm<256, 1><<<ggrid, 256, 0, stream>>>(nullptr, aggf, bkt, g0, be0,
                                            Wt1, as1, ad1, hb, asrc, adst, 4);
  k_softagg<4><<<NN / 4, 256, 0, stream>>>(rowst, csrc, asrc, adst, hb, b1, aggf,
                                           bkt + 32 * 512);

  // ---- layer 2 (BN1+ReLU fused; H=1 with slot partials)
  k_gemm<256, 1><<<ggrid, 256, 0, stream>>>(nullptr, aggf, bkt + 32 * 512, g1, be1,
                                            Wt2, as2, ad2, hb, asrc, adst, 1);
  k_softagg<1><<<NN / 4, 256, 0, stream>>>(rowst, csrc, asrc, adst, hb, b2, aggf,
                                           bkt + 2 * 32 * 512);

  // ---- final BN -> out (f32)
  k_bnred<<<1, 256, 0, stream>>>(bkt + 2 * 32 * 512, g2, be2, rsg2, sh2);
  k_bnout<<<NN / 4, 256, 0, stream>>>(aggf, rsg2, sh2, out);
}

// Round 7
// 293.061 us; speedup vs baseline: 2.0871x; 1.1533x over previous
//
#include <hip/hip_runtime.h>
#include <math.h>

#define NN 10000
#define EE 320000
#define ET (EE + NN)   // 330000 edges incl. self-loops

typedef __attribute__((ext_vector_type(8))) short short8;          // 8 x bf16
typedef __attribute__((ext_vector_type(8))) unsigned short ushort8_t;
typedef __attribute__((ext_vector_type(4))) float f32x4;
typedef unsigned short u16;

static __device__ __forceinline__ float b2f(u16 u) {
  return __uint_as_float(((unsigned)u) << 16);
}
static __device__ __forceinline__ u16 f2b(float f) {
  unsigned u = __float_as_uint(f);
  unsigned r = (u + 0x7FFFu + ((u >> 16) & 1u)) >> 16;  // RNE
  return (u16)r;
}

// ---------------------------------------------------------------- casts + degree count (fused)
__global__ void k_castcnt(const int* __restrict__ ei, int* __restrict__ cnt,
                          const float* __restrict__ x, const float* __restrict__ W0,
                          const float* __restrict__ W1, const float* __restrict__ W2,
                          u16* __restrict__ abf, u16* __restrict__ Wt0,
                          u16* __restrict__ Wt1, u16* __restrict__ Wt2) {
  int t = blockIdx.x * 256 + threadIdx.x;
  if (t < EE) atomicAdd(&cnt[ei[EE + t]], 1);
  const int NX4 = NN * 128 / 4;  // 320000
  if (t < NX4) {
    float4 f = ((const float4*)x)[t];
    ushort4 o;
    o.x = f2b(f.x); o.y = f2b(f.y); o.z = f2b(f.z); o.w = f2b(f.w);
    ((ushort4*)abf)[t] = o;
    return;
  }
  int u = t - NX4;
  if (u < 128 * 256) {
    int nI = u / 128, k = u - nI * 128;
    Wt0[u] = f2b(W0[(size_t)k * 256 + nI]);
    return;
  }
  u -= 128 * 256;
  if (u < 256 * 256) {
    int nI = u / 256, k = u - nI * 256;
    Wt1[u] = f2b(W1[(size_t)k * 256 + nI]);
    return;
  }
  u -= 256 * 256;
  if (u < 256 * 256) {
    int nI = u / 256, k = u - nI * 256;
    Wt2[u] = f2b(W2[(size_t)k * 256 + nI]);
  }
}

// ---------------------------------------------------------------- CSR scan + fill
__global__ __launch_bounds__(1024) void k_scan(const int* __restrict__ cnt,
                                               int* __restrict__ rowst,
                                               int* __restrict__ cursor,
                                               int* __restrict__ csrc) {
  __shared__ int ws[16];
  int tid = threadIdx.x, lane = tid & 63, wv = tid >> 6;
  int base = tid * 10;
  int v[10];
  int tot = 0;
#pragma unroll
  for (int i = 0; i < 10; i++) {
    int idx = base + i;
    v[i] = (idx < NN) ? (cnt[idx] + 1) : 0;
    tot += v[i];
  }
  int sc = tot;
#pragma unroll
  for (int off = 1; off < 64; off <<= 1) {
    int t = __shfl_up(sc, off);
    if (lane >= off) sc += t;
  }
  if (lane == 63) ws[wv] = sc;
  __syncthreads();
  if (wv == 0 && lane < 16) {
    int val = ws[lane];
    int s = val;
#pragma unroll
    for (int off = 1; off < 16; off <<= 1) {
      int t = __shfl_up(s, off);
      if (lane >= off) s += t;
    }
    ws[lane] = s - val;
  }
  __syncthreads();
  int run = ws[wv] + sc - tot;
#pragma unroll
  for (int i = 0; i < 10; i++) {
    int idx = base + i;
    if (idx < NN) {
      rowst[idx] = run;
      csrc[run] = idx;        // self-loop at slot 0
      cursor[idx] = run + 1;
      run += v[i];
    }
  }
  if (tid == 1023) rowst[NN] = run;
}

__global__ void k_fill(const int* __restrict__ ei, int* __restrict__ cursor,
                       int* __restrict__ csrc) {
  int e = blockIdx.x * 256 + threadIdx.x;
  if (e < EE) {
    int d = ei[EE + e];
    int pos = atomicAdd(&cursor[d], 1);
    csrc[pos] = ei[e];
  }
}

// ---------------------------------------------------------------- MFMA GEMM (+BN in, +att dots out)
// Block = 64 rows x 128 cols, 4 waves. grid (157, 2).
// BN=1: A is bf16 PRE-BN; per-channel scale/shift from 32 bucket-partials,
// applied + ReLU inline before MFMA. Epilogue: attention dots from f32 acc.
// Slots asrc/adst[row*4+slot]: H=4 -> slot=head; H=1 -> {2y}=partial, {2y+1}=0.
template <int KK, int BN>
__global__ __launch_bounds__(256) void k_gemm(
    const u16* __restrict__ A, const float* __restrict__ bkt,
    const float* __restrict__ gam, const float* __restrict__ bet,
    const u16* __restrict__ Wt, const float* __restrict__ as,
    const float* __restrict__ ad, u16* __restrict__ hb,
    float* __restrict__ asrc, float* __restrict__ adst, int H) {
  __shared__ float2 bnp[256];
  if (BN) {
    int t = threadIdx.x;
    float s = 0.f, q = 0.f;
#pragma unroll 8
    for (int b = 0; b < 32; b++) {
      s += bkt[b * 512 + t];
      q += bkt[b * 512 + 256 + t];
    }
    float m = s * (1.0f / NN);
    float v = q * (1.0f / NN) - m * m;
    float rs = rsqrtf(v + 1e-5f) * gam[t];
    bnp[t] = make_float2(rs, bet[t] - m * rs);
    __syncthreads();
  }
  int wv = threadIdx.x >> 6, lane = threadIdx.x & 63;
  int row0 = blockIdx.x * 64 + wv * 16;
  int col0 = blockIdx.y * 128;
  int r = lane & 15, g = lane >> 4;
  f32x4 acc[8];
#pragma unroll
  for (int nt = 0; nt < 8; nt++) acc[nt] = (f32x4){0.f, 0.f, 0.f, 0.f};

  int ar = row0 + r;
  if (ar > NN - 1) ar = NN - 1;  // clamp (stores guarded)

#pragma unroll
  for (int ks = 0; ks < KK / 32; ks++) {
    short8 af;
    short8 raw = *(const short8*)(A + (size_t)ar * KK + ks * 32 + g * 8);
    if (BN == 0) {
      af = raw;
    } else {
      int c0 = ks * 32 + g * 8;
#pragma unroll
      for (int j = 0; j < 8; j++) {
        float2 p = bnp[c0 + j];
        float t = fmaxf(fmaf(b2f((u16)raw[j]), p.x, p.y), 0.f);
        af[j] = (short)f2b(t);
      }
    }
#pragma unroll
    for (int nt = 0; nt < 8; nt++) {
      short8 bf = *(const short8*)(Wt + (size_t)(col0 + nt * 16 + r) * KK + ks * 32 + g * 8);
      acc[nt] = __builtin_amdgcn_mfma_f32_16x16x32_bf16(af, bf, acc[nt], 0, 0, 0);
    }
  }
  // C/D: col = lane&15, row = (lane>>4)*4 + reg   [m89/m91]
#pragma unroll
  for (int nt = 0; nt < 8; nt++) {
    int col = col0 + nt * 16 + r;
#pragma unroll
    for (int q = 0; q < 4; q++) {
      int row = row0 + g * 4 + q;
      if (row < NN) hb[(size_t)row * 256 + col] = f2b(acc[nt][q]);
    }
  }
  // ---- attention-dot epilogue
  float asv[8], adv[8];
#pragma unroll
  for (int nt = 0; nt < 8; nt++) {
    asv[nt] = as[col0 + nt * 16 + r];
    adv[nt] = ad[col0 + nt * 16 + r];
  }
#pragma unroll
  for (int q = 0; q < 4; q++) {
    int row = row0 + g * 4 + q;
    if (H == 4) {
#pragma unroll
      for (int hh = 0; hh < 2; hh++) {
        float ps = 0.f, pd = 0.f;
#pragma unroll
        for (int k = 0; k < 4; k++) {
          ps = fmaf(acc[hh * 4 + k][q], asv[hh * 4 + k], ps);
          pd = fmaf(acc[hh * 4 + k][q], adv[hh * 4 + k], pd);
        }
#pragma unroll
        for (int off = 1; off < 16; off <<= 1) {
          ps += __shfl_xor(ps, off);
          pd += __shfl_xor(pd, off);
        }
        if (r == 0 && row < NN) {
          int slot = 2 * blockIdx.y + hh;
          asrc[row * 4 + slot] = ps;
          adst[row * 4 + slot] = pd;
        }
      }
    } else {
      float ps = 0.f, pd = 0.f;
#pragma unroll
      for (int nt = 0; nt < 8; nt++) {
        ps = fmaf(acc[nt][q], asv[nt], ps);
        pd = fmaf(acc[nt][q], adv[nt], pd);
      }
#pragma unroll
      for (int off = 1; off < 16; off <<= 1) {
        ps += __shfl_xor(ps, off);
        pd += __shfl_xor(pd, off);
      }
      if (r == 0 && row < NN) {
        int slot = 2 * blockIdx.y;
        asrc[row * 4 + slot] = ps;
        asrc[row * 4 + slot + 1] = 0.f;
        adst[row * 4 + slot] = pd;
        adst[row * 4 + slot + 1] = 0.f;
      }
    }
  }
}

// ---------------------------------------------------------------- fused softmax+agg (+BN partials)
// Phase A: wave softmax (lane-per-edge, ids+weights to LDS, zero-pad to x16).
// Phase B: 16-edge iterations; lane = (half = edge parity, cl = channel oct);
// ushort8 (16B) gathers -> 2 rows per wave-instr; parity combine via shfl_xor(32).
// BOUT=1 -> bf16 out (pre-BN, next gemm applies BN); BOUT=0 -> f32 out.
template <int H, int BOUT>
__global__ __launch_bounds__(256) void k_softagg(
    const int* __restrict__ rowst, const int* __restrict__ csrc,
    const float* __restrict__ asrc, const float* __restrict__ adst,
    const u16* __restrict__ hb, const float* __restrict__ bias,
    float* __restrict__ outf, u16* __restrict__ outb, float* __restrict__ bkt) {
  __shared__ int lds_s[4][128];
  __shared__ float lds_w[4][128][H];
  __shared__ float lds_v[4][256];
  __shared__ float lds_q[4][256];
  int wv = threadIdx.x >> 6, lane = threadIdx.x & 63;
  int n = blockIdx.x * 4 + wv;  // NN % 4 == 0
  int rs = rowst[n], re = rowst[n + 1];

  float ad[H];
  {
    float4 t = ((const float4*)adst)[n];
    if (H == 4) { ad[0] = t.x; ad[1] = t.y; ad[2] = t.z; ad[3] = t.w; }
    else ad[0] = t.x + t.y + t.z + t.w;
  }
  float mx[H], sm[H];
#pragma unroll
  for (int h = 0; h < H; h++) { mx[h] = -1e30f; sm[h] = 0.f; }

  int e0 = rs + lane, e1 = e0 + 64;
  bool h0 = e0 < re, h1 = e1 < re;
  float a0[H], a1[H];

  if (h0) {
    int s = csrc[e0];
    lds_s[wv][lane] = s;
    float4 t = ((const float4*)asrc)[s];
    if (H == 4) { a0[0] = t.x; a0[1] = t.y; a0[2] = t.z; a0[3] = t.w; }
    else a0[0] = t.x + t.y + t.z + t.w;
#pragma unroll
    for (int h = 0; h < H; h++) {
      float v = a0[h] + ad[h];
      v = v > 0.f ? v : 0.2f * v;
      a0[h] = v;
      mx[h] = fmaxf(mx[h], v);
    }
  }
  if (h1) {
    int s = csrc[e1];
    lds_s[wv][64 + lane] = s;
    float4 t = ((const float4*)asrc)[s];
    if (H == 4) { a1[0] = t.x; a1[1] = t.y; a1[2] = t.z; a1[3] = t.w; }
    else a1[0] = t.x + t.y + t.z + t.w;
#pragma unroll
    for (int h = 0; h < H; h++) {
      float v = a1[h] + ad[h];
      v = v > 0.f ? v : 0.2f * v;
      a1[h] = v;
      mx[h] = fmaxf(mx[h], v);
    }
  }
  for (int e = rs + 128 + lane; e < re; e += 64) {  // cold (deg>128): max only
    int s = csrc[e];
    float4 t = ((const float4*)asrc)[s];
    float a[H];
    if (H == 4) { a[0] = t.x; a[1] = t.y; a[2] = t.z; a[3] = t.w; }
    else a[0] = t.x + t.y + t.z + t.w;
#pragma unroll
    for (int h = 0; h < H; h++) {
      float v = a[h] + ad[h];
      v = v > 0.f ? v : 0.2f * v;
      mx[h] = fmaxf(mx[h], v);
    }
  }
#pragma unroll
  for (int off = 32; off; off >>= 1)
#pragma unroll
    for (int h = 0; h < H; h++) mx[h] = fmaxf(mx[h], __shfl_xor(mx[h], off));

  if (h0) {
#pragma unroll
    for (int h = 0; h < H; h++) {
      a0[h] = __expf(a0[h] - mx[h]);
      sm[h] += a0[h];
      lds_w[wv][lane][h] = a0[h];
    }
  }
  if (h1) {
#pragma unroll
    for (int h = 0; h < H; h++) {
      a1[h] = __expf(a1[h] - mx[h]);
      sm[h] += a1[h];
      lds_w[wv][64 + lane][h] = a1[h];
    }
  }
  for (int e = rs + 128 + lane; e < re; e += 64) {  // cold: exp+sum
    int s = csrc[e];
    float4 t = ((const float4*)asrc)[s];
    float a[H];
    if (H == 4) { a[0] = t.x; a[1] = t.y; a[2] = t.z; a[3] = t.w; }
    else a[0] = t.x + t.y + t.z + t.w;
#pragma unroll
    for (int h = 0; h < H; h++) {
      float v = a[h] + ad[h];
      v = v > 0.f ? v : 0.2f * v;
      sm[h] += __expf(v - mx[h]);
    }
  }
#pragma unroll
  for (int off = 32; off; off >>= 1)
#pragma unroll
    for (int h = 0; h < H; h++) sm[h] += __shfl_xor(sm[h], off);

  float inv[H];
#pragma unroll
  for (int h = 0; h < H; h++) inv[h] = 1.0f / (sm[h] + 1e-16f);

  // ---- zero-pad LDS slots up to a multiple of 16
  int m = re - rs;
  if (m > 128) m = 128;
  int mp = (m + 15) & ~15;
  for (int p = m + lane; p < mp; p += 64) {
    lds_s[wv][p] = n;  // valid row; weight 0
#pragma unroll
    for (int h = 0; h < H; h++) lds_w[wv][p][h] = 0.f;
  }

  // ---- phase B: aggregation (lane = parity x channel-oct)
  int cl = lane & 31, half = lane >> 5;
  int hd8 = (H == 4) ? (cl >> 3) : 0;
  float invh = (H == 4) ? (hd8 == 0 ? inv[0] : hd8 == 1 ? inv[1] : hd8 == 2 ? inv[2] : inv[3])
                        : inv[0];
  float mh = (H == 4) ? (hd8 == 0 ? mx[0] : hd8 == 1 ? mx[1] : hd8 == 2 ? mx[2] : mx[3])
                      : mx[0];
  float adh = (H == 4) ? (hd8 == 0 ? ad[0] : hd8 == 1 ? ad[1] : hd8 == 2 ? ad[2] : ad[3])
                       : ad[0];
  const ushort8_t* h8 = (const ushort8_t*)hb;
  float acc[8] = {0.f, 0.f, 0.f, 0.f, 0.f, 0.f, 0.f, 0.f};
  for (int e = 0; e < mp; e += 16) {
    int ss[8];
    float ww[8];
    ushort8_t vv[8];
#pragma unroll
    for (int j = 0; j < 8; j++) ss[j] = lds_s[wv][e + 2 * j + half];
#pragma unroll
    for (int j = 0; j < 8; j++) ww[j] = lds_w[wv][e + 2 * j + half][hd8];
#pragma unroll
    for (int j = 0; j < 8; j++) vv[j] = h8[(size_t)ss[j] * 32 + cl];
#pragma unroll
    for (int j = 0; j < 8; j++)
#pragma unroll
      for (int k = 0; k < 8; k++) acc[k] = fmaf(ww[j], b2f((u16)vv[j][k]), acc[k]);
  }
  for (int ee = rs + 128 + half; ee < re; ee += 2) {  // cold: recompute w, parity split
    int s = csrc[ee];
    float4 t = ((const float4*)asrc)[s];
    float av = (H == 4) ? (hd8 == 0 ? t.x : hd8 == 1 ? t.y : hd8 == 2 ? t.z : t.w)
                        : (t.x + t.y + t.z + t.w);
    float vv2 = av + adh;
    vv2 = vv2 > 0.f ? vv2 : 0.2f * vv2;
    float w = __expf(vv2 - mh);
    ushort8_t v = h8[(size_t)s * 32 + cl];
#pragma unroll
    for (int k = 0; k < 8; k++) acc[k] = fmaf(w, b2f((u16)v[k]), acc[k]);
  }
#pragma unroll
  for (int k = 0; k < 8; k++) acc[k] += __shfl_xor(acc[k], 32);

  float4 ba = ((const float4*)bias)[cl * 2];
  float4 bb = ((const float4*)bias)[cl * 2 + 1];
  float r8[8];
  r8[0] = acc[0] * invh + ba.x; r8[1] = acc[1] * invh + ba.y;
  r8[2] = acc[2] * invh + ba.z; r8[3] = acc[3] * invh + ba.w;
  r8[4] = acc[4] * invh + bb.x; r8[5] = acc[5] * invh + bb.y;
  r8[6] = acc[6] * invh + bb.z; r8[7] = acc[7] * invh + bb.w;

  if (half == 0) {
    if (BOUT) {
      ushort8_t o;
#pragma unroll
      for (int k = 0; k < 8; k++) o[k] = f2b(r8[k]);
      ((ushort8_t*)outb)[(size_t)n * 32 + cl] = o;
    } else {
      float4 w0 = make_float4(r8[0], r8[1], r8[2], r8[3]);
      float4 w1 = make_float4(r8[4], r8[5], r8[6], r8[7]);
      ((float4*)outf)[(size_t)n * 64 + cl * 2] = w0;
      ((float4*)outf)[(size_t)n * 64 + cl * 2 + 1] = w1;
    }
#pragma unroll
    for (int k = 0; k < 8; k++) {
      lds_v[wv][cl * 8 + k] = r8[k];
      lds_q[wv][cl * 8 + k] = r8[k] * r8[k];
    }
  }
  __syncthreads();
  // ---- BN partials: 256 threads, channel t, 2 atomics each into 32 buckets
  int t = threadIdx.x;
  float sv = lds_v[0][t] + lds_v[1][t] + lds_v[2][t] + lds_v[3][t];
  float sq = lds_q[0][t] + lds_q[1][t] + lds_q[2][t] + lds_q[3][t];
  float* pv = bkt + (blockIdx.x & 31) * 512;
  atomicAdd(pv + t, sv);
  atomicAdd(pv + 256 + t, sq);
}

// ---------------------------------------------------------------- final BN
__global__ void k_bnred(const float* __restrict__ bkt, const float* __restrict__ g,
                        const float* __restrict__ be, float* __restrict__ rsg,
                        float* __restrict__ sh) {
  int t = threadIdx.x;  // 256
  float s = 0.f, q = 0.f;
#pragma unroll 8
  for (int b = 0; b < 32; b++) {
    s += bkt[b * 512 + t];
    q += bkt[b * 512 + 256 + t];
  }
  float m = s * (1.0f / NN);
  float v = q * (1.0f / NN) - m * m;
  float rs = rsqrtf(v + 1e-5f) * g[t];
  rsg[t] = rs;
  sh[t] = be[t] - m * rs;
}

__global__ void k_bnout(const float* __restrict__ x, const float* __restrict__ rsg,
                        const float* __restrict__ sh, float* __restrict__ y) {
  int i = blockIdx.x * 256 + threadIdx.x;  // float4 index over NN*64
  int c = i & 63;
  float4 rs4 = ((const float4*)rsg)[c];
  float4 sh4 = ((const float4*)sh)[c];
  float4 xv = ((const float4*)x)[i];
  float4 r;
  r.x = fmaf(xv.x, rs4.x, sh4.x);
  r.y = fmaf(xv.y, rs4.y, sh4.y);
  r.z = fmaf(xv.z, rs4.z, sh4.z);
  r.w = fmaf(xv.w, rs4.w, sh4.w);
  ((float4*)y)[i] = r;
}

// ---------------------------------------------------------------- launch
extern "C" void kernel_launch(void* const* d_in, const int* in_sizes, int n_in,
                              void* d_out, int out_size, void* d_ws, size_t ws_size,
                              hipStream_t stream) {
  const float* x   = (const float*)d_in[0];
  const int*   ei  = (const int*)d_in[1];
  const float* W0  = (const float*)d_in[2];
  const float* as0 = (const float*)d_in[3];
  const float* ad0 = (const float*)d_in[4];
  const float* b0  = (const float*)d_in[5];
  const float* g0  = (const float*)d_in[6];
  const float* be0 = (const float*)d_in[7];
  const float* W1  = (const float*)d_in[8];
  const float* as1 = (const float*)d_in[9];
  const float* ad1 = (const float*)d_in[10];
  const float* b1  = (const float*)d_in[11];
  const float* g1  = (const float*)d_in[12];
  const float* be1 = (const float*)d_in[13];
  const float* W2  = (const float*)d_in[14];
  const float* as2 = (const float*)d_in[15];
  const float* ad2 = (const float*)d_in[16];
  const float* b2  = (const float*)d_in[17];
  const float* g2  = (const float*)d_in[18];
  const float* be2 = (const float*)d_in[19];
  float* out = (float*)d_out;

  // workspace layout (~25.3 MB)
  u16* hb   = (u16*)d_ws;                   // NN*256 bf16
  u16* abf  = hb + (size_t)NN * 256;        // NN*128 bf16 (layer-0 input)
  u16* ab16 = abf + (size_t)NN * 128;       // NN*256 bf16 (inter-layer, pre-BN)
  u16* Wt0  = ab16 + (size_t)NN * 256;      // 256*128
  u16* Wt1  = Wt0 + 256 * 128;              // 256*256
  u16* Wt2  = Wt1 + 256 * 256;              // 256*256
  float* asrc = (float*)(Wt2 + 256 * 256);  // NN*4
  float* adst = asrc + NN * 4;              // NN*4
  float* aggf = adst + NN * 4;              // NN*256 f32 (final layer only)
  float* bkt  = aggf + (size_t)NN * 256;    // 3 * 32 * 512
  float* rsg2 = bkt + 3 * 32 * 512;         // 256
  float* sh2  = rsg2 + 256;                 // 256
  int* cnt    = (int*)(sh2 + 256);          // NN (adjacent -> one memset)
  int* rowst  = cnt + NN;                   // NN+1
  int* cursor = rowst + NN + 1;             // NN
  int* csrc   = cursor + NN;                // ET

  // ---- one memset covers buckets + rsg/sh + cnt
  hipMemsetAsync(bkt, 0, (3 * 32 * 512 + 512 + NN) * sizeof(float), stream);
  {
    int total = NN * 128 / 4 + 128 * 256 + 256 * 256 + 256 * 256;  // 483840
    k_castcnt<<<(total + 255) / 256, 256, 0, stream>>>(ei, cnt, x, W0, W1, W2,
                                                       abf, Wt0, Wt1, Wt2);
  }
  k_scan<<<1, 1024, 0, stream>>>(cnt, rowst, cursor, csrc);
  k_fill<<<(EE + 255) / 256, 256, 0, stream>>>(ei, cursor, csrc);

  dim3 ggrid((NN + 63) / 64, 2);

  // ---- layer 0 (no input BN) -> ab16 (pre-BN bf16)
  k_gemm<128, 0><<<ggrid, 256, 0, stream>>>(abf, nullptr, nullptr, nullptr,
                                            Wt0, as0, ad0, hb, asrc, adst, 4);
  k_softagg<4, 1><<<NN / 4, 256, 0, stream>>>(rowst, csrc, asrc, adst, hb, b0,
                                              nullptr, ab16, bkt);

  // ---- layer 1 (BN0+ReLU fused into A-load) -> ab16
  k_gemm<256, 1><<<ggrid, 256, 0, stream>>>(ab16, bkt, g0, be0,
                                            Wt1, as1, ad1, hb, asrc, adst, 4);
  k_softagg<4, 1><<<NN / 4, 256, 0, stream>>>(rowst, csrc, asrc, adst, hb, b1,
                                              nullptr, ab16, bkt + 32 * 512);

  // ---- layer 2 (BN1+ReLU fused; H=1 slot partials) -> aggf f32
  k_gemm<256, 1><<<ggrid, 256, 0, stream>>>(ab16, bkt + 32 * 512, g1, be1,
                                            Wt2, as2, ad2, hb, asrc, adst, 1);
  k_softagg<1, 0><<<NN / 4, 256, 0, stream>>>(rowst, csrc, asrc, adst, hb, b2,
                                              aggf, nullptr, bkt + 2 * 32 * 512);

  // ---- final BN -> out (f32)
  k_bnred<<<1, 256, 0, stream>>>(bkt + 2 * 32 * 512, g2, be2, rsg2, sh2);
  k_bnout<<<NN / 4, 256, 0, stream>>>(aggf, rsg2, sh2, out);
}

// Round 8
// 282.011 us; speedup vs baseline: 2.1688x; 1.0392x over previous
//
#include <hip/hip_runtime.h>
#include <math.h>

#define NN 10000
#define EE 320000
#define ET (EE + NN)   // 330000 edges incl. self-loops
#define HBROWS 10048   // hb padded to grid rows (157*64)

typedef __attribute__((ext_vector_type(8))) short short8;          // 8 x bf16
typedef __attribute__((ext_vector_type(8))) unsigned short ushort8_t;
typedef __attribute__((ext_vector_type(4))) float f32x4;
typedef unsigned short u16;

static __device__ __forceinline__ float b2f(u16 u) {
  return __uint_as_float(((unsigned)u) << 16);
}
static __device__ __forceinline__ u16 f2b(float f) {
  unsigned u = __float_as_uint(f);
  unsigned r = (u + 0x7FFFu + ((u >> 16) & 1u)) >> 16;  // RNE
  return (u16)r;
}

// ---------------------------------------------------------------- casts + degree count
// blocks [0,1250): e-range — degree count atomic + x->bf16 cast (same index range)
// blocks [1250,1290): one 64x64 W-transpose tile each (LDS, coalesced both sides)
__global__ __launch_bounds__(256) void k_castcnt(
    const int* __restrict__ ei, int* __restrict__ cnt, const float* __restrict__ x,
    const float* __restrict__ W0, const float* __restrict__ W1,
    const float* __restrict__ W2, u16* __restrict__ abf, u16* __restrict__ Wt0,
    u16* __restrict__ Wt1, u16* __restrict__ Wt2) {
  int b = blockIdx.x, tid = threadIdx.x;
  if (b < 1250) {
    int e = b * 256 + tid;  // < 320000 == EE == NN*128/4
    atomicAdd(&cnt[ei[EE + e]], 1);
    float4 f = ((const float4*)x)[e];
    ushort4 o;
    o.x = f2b(f.x); o.y = f2b(f.y); o.z = f2b(f.z); o.w = f2b(f.w);
    ((ushort4*)abf)[e] = o;
    return;
  }
  __shared__ float tile[64][65];
  int wt = b - 1250;
  const float* W; u16* Wt; int K, kt, nt_;
  if (wt < 8)       { W = W0; Wt = Wt0; K = 128; kt = wt & 1; nt_ = wt >> 1; }
  else if (wt < 24) { W = W1; Wt = Wt1; K = 256; int u = wt - 8;  kt = u & 3; nt_ = u >> 2; }
  else              { W = W2; Wt = Wt2; K = 256; int u = wt - 24; kt = u & 3; nt_ = u >> 2; }
  int k0 = kt * 64, n0 = nt_ * 64;
  int tx = tid & 63, ty = tid >> 6;
#pragma unroll
  for (int it = 0; it < 16; it++) {
    int row = it * 4 + ty;
    tile[row][tx] = W[(size_t)(k0 + row) * 256 + n0 + tx];
  }
  __syncthreads();
#pragma unroll
  for (int it = 0; it < 16; it++) {
    int row = it * 4 + ty;
    Wt[(size_t)(n0 + row) * K + k0 + tx] = f2b(tile[tx][row]);
  }
}

// ---------------------------------------------------------------- CSR scan
__global__ __launch_bounds__(1024) void k_scan(const int* __restrict__ cnt,
                                               int* __restrict__ rowst,
                                               int* __restrict__ cursor,
                                               int* __restrict__ csrc) {
  __shared__ int ws[16];
  int tid = threadIdx.x, lane = tid & 63, wv = tid >> 6;
  int base = tid * 10;
  int v[10];
  int tot = 0;
#pragma unroll
  for (int i = 0; i < 10; i++) {
    int idx = base + i;
    v[i] = (idx < NN) ? (cnt[idx] + 1) : 0;
    tot += v[i];
  }
  int sc = tot;
#pragma unroll
  for (int off = 1; off < 64; off <<= 1) {
    int t = __shfl_up(sc, off);
    if (lane >= off) sc += t;
  }
  if (lane == 63) ws[wv] = sc;
  __syncthreads();
  if (wv == 0 && lane < 16) {
    int val = ws[lane];
    int s = val;
#pragma unroll
    for (int off = 1; off < 16; off <<= 1) {
      int t = __shfl_up(s, off);
      if (lane >= off) s += t;
    }
    ws[lane] = s - val;
  }
  __syncthreads();
  int run = ws[wv] + sc - tot;
#pragma unroll
  for (int i = 0; i < 10; i++) {
    int idx = base + i;
    if (idx < NN) {
      rowst[idx] = run;
      csrc[run] = idx;        // self-loop at slot 0
      cursor[idx] = run + 1;
      run += v[i];
    }
  }
  if (tid == 1023) rowst[NN] = run;
}

// ---------------------------------------------------------------- MFMA GEMM (+BN in, +dots, +opt fill)
// gemm units: flattened b in [0,314): gx=b>>1, gy=b&1. Block=64rx128c, 4 waves.
// FILL=1: blocks [314,314+1250) do the CSR edge-fill instead (overlapped work).
// BN=1: A bf16 pre-BN; scale/shift from buckets applied + ReLU before MFMA.
// C-store: per-wave LDS transpose -> 4x coalesced 16B stores per lane.
// Dots: H=4 slot=head; H=1 slots {2y}=col-half partial, {2y+1}=0.
template <int KK, int BN, int FILL>
__global__ __launch_bounds__(256) void k_gemm(
    const u16* __restrict__ A, const float* __restrict__ bkt,
    const float* __restrict__ gam, const float* __restrict__ bet,
    const u16* __restrict__ Wt, const float* __restrict__ as,
    const float* __restrict__ ad, u16* __restrict__ hb,
    float* __restrict__ asrc, float* __restrict__ adst, int H,
    const int* __restrict__ ei, int* __restrict__ cursor, int* __restrict__ csrc) {
  if (FILL && blockIdx.x >= 314) {
    int e = (blockIdx.x - 314) * 256 + threadIdx.x;
    if (e < EE) {
      int d = ei[EE + e];
      int pos = atomicAdd(&cursor[d], 1);
      csrc[pos] = ei[e];
    }
    return;
  }
  __shared__ float2 bnp[256];
  __shared__ u16 lds_c[4][16][136];
  if (BN) {
    int t = threadIdx.x;
    float s = 0.f, q = 0.f;
#pragma unroll 8
    for (int b = 0; b < 32; b++) {
      s += bkt[b * 512 + t];
      q += bkt[b * 512 + 256 + t];
    }
    float m = s * (1.0f / NN);
    float v = q * (1.0f / NN) - m * m;
    float rs = rsqrtf(v + 1e-5f) * gam[t];
    bnp[t] = make_float2(rs, bet[t] - m * rs);
    __syncthreads();
  }
  int wv = threadIdx.x >> 6, lane = threadIdx.x & 63;
  int gx = blockIdx.x >> 1, gy = blockIdx.x & 1;
  int row0 = gx * 64 + wv * 16;
  int col0 = gy * 128;
  int r = lane & 15, g = lane >> 4;
  f32x4 acc[8];
#pragma unroll
  for (int nt = 0; nt < 8; nt++) acc[nt] = (f32x4){0.f, 0.f, 0.f, 0.f};

  int ar = row0 + r;
  if (ar > NN - 1) ar = NN - 1;  // clamp A reads

#pragma unroll
  for (int ks = 0; ks < KK / 32; ks++) {
    short8 af;
    short8 raw = *(const short8*)(A + (size_t)ar * KK + ks * 32 + g * 8);
    if (BN == 0) {
      af = raw;
    } else {
      int c0 = ks * 32 + g * 8;
#pragma unroll
      for (int j = 0; j < 8; j++) {
        float2 p = bnp[c0 + j];
        float t = fmaxf(fmaf(b2f((u16)raw[j]), p.x, p.y), 0.f);
        af[j] = (short)f2b(t);
      }
    }
#pragma unroll
    for (int nt = 0; nt < 8; nt++) {
      short8 bf = *(const short8*)(Wt + (size_t)(col0 + nt * 16 + r) * KK + ks * 32 + g * 8);
      acc[nt] = __builtin_amdgcn_mfma_f32_16x16x32_bf16(af, bf, acc[nt], 0, 0, 0);
    }
  }
  // ---- C-store: wave-local LDS transpose, then coalesced ushort8 stores
  // C/D: col = lane&15, row = (lane>>4)*4 + reg   [m89/m91]
#pragma unroll
  for (int nt = 0; nt < 8; nt++)
#pragma unroll
    for (int q = 0; q < 4; q++)
      lds_c[wv][g * 4 + q][nt * 16 + r] = f2b(acc[nt][q]);
#pragma unroll
  for (int j = 0; j < 4; j++) {
    int c = j * 64 + lane;
    int row = c >> 4, off = (c & 15) * 8;
    ushort8_t vv = *(const ushort8_t*)&lds_c[wv][row][off];
    *(ushort8_t*)&hb[(size_t)(row0 + row) * 256 + col0 + off] = vv;
  }
  // ---- attention-dot epilogue (f32 acc)
  float asv[8], adv[8];
#pragma unroll
  for (int nt = 0; nt < 8; nt++) {
    asv[nt] = as[col0 + nt * 16 + r];
    adv[nt] = ad[col0 + nt * 16 + r];
  }
#pragma unroll
  for (int q = 0; q < 4; q++) {
    int row = row0 + g * 4 + q;
    if (H == 4) {
#pragma unroll
      for (int hh = 0; hh < 2; hh++) {
        float ps = 0.f, pd = 0.f;
#pragma unroll
        for (int k = 0; k < 4; k++) {
          ps = fmaf(acc[hh * 4 + k][q], asv[hh * 4 + k], ps);
          pd = fmaf(acc[hh * 4 + k][q], adv[hh * 4 + k], pd);
        }
#pragma unroll
        for (int off = 1; off < 16; off <<= 1) {
          ps += __shfl_xor(ps, off);
          pd += __shfl_xor(pd, off);
        }
        if (r == 0 && row < NN) {
          int slot = 2 * gy + hh;
          asrc[row * 4 + slot] = ps;
          adst[row * 4 + slot] = pd;
        }
      }
    } else {
      float ps = 0.f, pd = 0.f;
#pragma unroll
      for (int nt = 0; nt < 8; nt++) {
        ps = fmaf(acc[nt][q], asv[nt], ps);
        pd = fmaf(acc[nt][q], adv[nt], pd);
      }
#pragma unroll
      for (int off = 1; off < 16; off <<= 1) {
        ps += __shfl_xor(ps, off);
        pd += __shfl_xor(pd, off);
      }
      if (r == 0 && row < NN) {
        int slot = 2 * gy;
        asrc[row * 4 + slot] = ps;
        asrc[row * 4 + slot + 1] = 0.f;
        adst[row * 4 + slot] = pd;
        adst[row * 4 + slot + 1] = 0.f;
      }
    }
  }
}

// ---------------------------------------------------------------- fused softmax+agg (+BN partials)
template <int H, int BOUT>
__global__ __launch_bounds__(256) void k_softagg(
    const int* __restrict__ rowst, const int* __restrict__ csrc,
    const float* __restrict__ asrc, const float* __restrict__ adst,
    const u16* __restrict__ hb, const float* __restrict__ bias,
    float* __restrict__ outf, u16* __restrict__ outb, float* __restrict__ bkt) {
  __shared__ int lds_s[4][128];
  __shared__ float lds_w[4][128][H];
  __shared__ float lds_v[4][256];
  __shared__ float lds_q[4][256];
  int wv = threadIdx.x >> 6, lane = threadIdx.x & 63;
  int n = blockIdx.x * 4 + wv;  // NN % 4 == 0
  int rs = rowst[n], re = rowst[n + 1];

  float ad[H];
  {
    float4 t = ((const float4*)adst)[n];
    if (H == 4) { ad[0] = t.x; ad[1] = t.y; ad[2] = t.z; ad[3] = t.w; }
    else ad[0] = t.x + t.y + t.z + t.w;
  }
  float mx[H], sm[H];
#pragma unroll
  for (int h = 0; h < H; h++) { mx[h] = -1e30f; sm[h] = 0.f; }

  int e0 = rs + lane, e1 = e0 + 64;
  bool h0 = e0 < re, h1 = e1 < re;
  float a0[H], a1[H];

  if (h0) {
    int s = csrc[e0];
    lds_s[wv][lane] = s;
    float4 t = ((const float4*)asrc)[s];
    if (H == 4) { a0[0] = t.x; a0[1] = t.y; a0[2] = t.z; a0[3] = t.w; }
    else a0[0] = t.x + t.y + t.z + t.w;
#pragma unroll
    for (int h = 0; h < H; h++) {
      float v = a0[h] + ad[h];
      v = v > 0.f ? v : 0.2f * v;
      a0[h] = v;
      mx[h] = fmaxf(mx[h], v);
    }
  }
  if (h1) {
    int s = csrc[e1];
    lds_s[wv][64 + lane] = s;
    float4 t = ((const float4*)asrc)[s];
    if (H == 4) { a1[0] = t.x; a1[1] = t.y; a1[2] = t.z; a1[3] = t.w; }
    else a1[0] = t.x + t.y + t.z + t.w;
#pragma unroll
    for (int h = 0; h < H; h++) {
      float v = a1[h] + ad[h];
      v = v > 0.f ? v : 0.2f * v;
      a1[h] = v;
      mx[h] = fmaxf(mx[h], v);
    }
  }
  for (int e = rs + 128 + lane; e < re; e += 64) {  // cold (deg>128): max only
    int s = csrc[e];
    float4 t = ((const float4*)asrc)[s];
    float a[H];
    if (H == 4) { a[0] = t.x; a[1] = t.y; a[2] = t.z; a[3] = t.w; }
    else a[0] = t.x + t.y + t.z + t.w;
#pragma unroll
    for (int h = 0; h < H; h++) {
      float v = a[h] + ad[h];
      v = v > 0.f ? v : 0.2f * v;
      mx[h] = fmaxf(mx[h], v);
    }
  }
#pragma unroll
  for (int off = 32; off; off >>= 1)
#pragma unroll
    for (int h = 0; h < H; h++) mx[h] = fmaxf(mx[h], __shfl_xor(mx[h], off));

  if (h0) {
#pragma unroll
    for (int h = 0; h < H; h++) {
      a0[h] = __expf(a0[h] - mx[h]);
      sm[h] += a0[h];
      lds_w[wv][lane][h] = a0[h];
    }
  }
  if (h1) {
#pragma unroll
    for (int h = 0; h < H; h++) {
      a1[h] = __expf(a1[h] - mx[h]);
      sm[h] += a1[h];
      lds_w[wv][64 + lane][h] = a1[h];
    }
  }
  for (int e = rs + 128 + lane; e < re; e += 64) {  // cold: exp+sum
    int s = csrc[e];
    float4 t = ((const float4*)asrc)[s];
    float a[H];
    if (H == 4) { a[0] = t.x; a[1] = t.y; a[2] = t.z; a[3] = t.w; }
    else a[0] = t.x + t.y + t.z + t.w;
#pragma unroll
    for (int h = 0; h < H; h++) {
      float v = a[h] + ad[h];
      v = v > 0.f ? v : 0.2f * v;
      sm[h] += __expf(v - mx[h]);
    }
  }
#pragma unroll
  for (int off = 32; off; off >>= 1)
#pragma unroll
    for (int h = 0; h < H; h++) sm[h] += __shfl_xor(sm[h], off);

  float inv[H];
#pragma unroll
  for (int h = 0; h < H; h++) inv[h] = 1.0f / (sm[h] + 1e-16f);

  // ---- zero-pad LDS slots up to a multiple of 16
  int m = re - rs;
  if (m > 128) m = 128;
  int mp = (m + 15) & ~15;
  for (int p = m + lane; p < mp; p += 64) {
    lds_s[wv][p] = n;  // valid row; weight 0
#pragma unroll
    for (int h = 0; h < H; h++) lds_w[wv][p][h] = 0.f;
  }

  // ---- phase B: aggregation (lane = parity x channel-oct)
  int cl = lane & 31, half = lane >> 5;
  int hd8 = (H == 4) ? (cl >> 3) : 0;
  float invh = (H == 4) ? (hd8 == 0 ? inv[0] : hd8 == 1 ? inv[1] : hd8 == 2 ? inv[2] : inv[3])
                        : inv[0];
  float mh = (H == 4) ? (hd8 == 0 ? mx[0] : hd8 == 1 ? mx[1] : hd8 == 2 ? mx[2] : mx[3])
                      : mx[0];
  float adh = (H == 4) ? (hd8 == 0 ? ad[0] : hd8 == 1 ? ad[1] : hd8 == 2 ? ad[2] : ad[3])
                       : ad[0];
  const ushort8_t* h8 = (const ushort8_t*)hb;
  float acc[8] = {0.f, 0.f, 0.f, 0.f, 0.f, 0.f, 0.f, 0.f};
  for (int e = 0; e < mp; e += 16) {
    int ss[8];
    float ww[8];
    ushort8_t vv[8];
#pragma unroll
    for (int j = 0; j < 8; j++) ss[j] = lds_s[wv][e + 2 * j + half];
#pragma unroll
    for (int j = 0; j < 8; j++) ww[j] = lds_w[wv][e + 2 * j + half][hd8];
#pragma unroll
    for (int j = 0; j < 8; j++) vv[j] = h8[(size_t)ss[j] * 32 + cl];
#pragma unroll
    for (int j = 0; j < 8; j++)
#pragma unroll
      for (int k = 0; k < 8; k++) acc[k] = fmaf(ww[j], b2f((u16)vv[j][k]), acc[k]);
  }
  for (int ee = rs + 128 + half; ee < re; ee += 2) {  // cold: recompute w
    int s = csrc[ee];
    float4 t = ((const float4*)asrc)[s];
    float av = (H == 4) ? (hd8 == 0 ? t.x : hd8 == 1 ? t.y : hd8 == 2 ? t.z : t.w)
                        : (t.x + t.y + t.z + t.w);
    float vv2 = av + adh;
    vv2 = vv2 > 0.f ? vv2 : 0.2f * vv2;
    float w = __expf(vv2 - mh);
    ushort8_t v = h8[(size_t)s * 32 + cl];
#pragma unroll
    for (int k = 0; k < 8; k++) acc[k] = fmaf(w, b2f((u16)v[k]), acc[k]);
  }
#pragma unroll
  for (int k = 0; k < 8; k++) acc[k] += __shfl_xor(acc[k], 32);

  float4 ba = ((const float4*)bias)[cl * 2];
  float4 bb = ((const float4*)bias)[cl * 2 + 1];
  float r8[8];
  r8[0] = acc[0] * invh + ba.x; r8[1] = acc[1] * invh + ba.y;
  r8[2] = acc[2] * invh + ba.z; r8[3] = acc[3] * invh + ba.w;
  r8[4] = acc[4] * invh + bb.x; r8[5] = acc[5] * invh + bb.y;
  r8[6] = acc[6] * invh + bb.z; r8[7] = acc[7] * invh + bb.w;

  if (half == 0) {
    if (BOUT) {
      ushort8_t o;
#pragma unroll
      for (int k = 0; k < 8; k++) o[k] = f2b(r8[k]);
      ((ushort8_t*)outb)[(size_t)n * 32 + cl] = o;
    } else {
      float4 w0 = make_float4(r8[0], r8[1], r8[2], r8[3]);
      float4 w1 = make_float4(r8[4], r8[5], r8[6], r8[7]);
      ((float4*)outf)[(size_t)n * 64 + cl * 2] = w0;
      ((float4*)outf)[(size_t)n * 64 + cl * 2 + 1] = w1;
    }
#pragma unroll
    for (int k = 0; k < 8; k++) {
      lds_v[wv][cl * 8 + k] = r8[k];
      lds_q[wv][cl * 8 + k] = r8[k] * r8[k];
    }
  }
  __syncthreads();
  // ---- BN partials: 256 threads, channel t, 2 atomics into 32 buckets
  int t = threadIdx.x;
  float sv = lds_v[0][t] + lds_v[1][t] + lds_v[2][t] + lds_v[3][t];
  float sq = lds_q[0][t] + lds_q[1][t] + lds_q[2][t] + lds_q[3][t];
  float* pv = bkt + (blockIdx.x & 31) * 512;
  atomicAdd(pv + t, sv);
  atomicAdd(pv + 256 + t, sq);
}

// ---------------------------------------------------------------- final BN (red+apply fused)
__global__ __launch_bounds__(256) void k_bnout(const float* __restrict__ bkt,
                                               const float* __restrict__ g,
                                               const float* __restrict__ be,
                                               const float* __restrict__ x,
                                               float* __restrict__ y) {
  __shared__ float2 p[256];
  int t = threadIdx.x;
  float s = 0.f, q = 0.f;
#pragma unroll 8
  for (int b = 0; b < 32; b++) {
    s += bkt[b * 512 + t];
    q += bkt[b * 512 + 256 + t];
  }
  float m = s * (1.0f / NN);
  float v = q * (1.0f / NN) - m * m;
  float rs = rsqrtf(v + 1e-5f) * g[t];
  p[t] = make_float2(rs, be[t] - m * rs);
  __syncthreads();
  int i = blockIdx.x * 256 + t;  // float4 index over NN*64
  int c = i & 63;
  float2 p0 = p[c * 4], p1 = p[c * 4 + 1], p2 = p[c * 4 + 2], p3 = p[c * 4 + 3];
  float4 xv = ((const float4*)x)[i];
  float4 r;
  r.x = fmaf(xv.x, p0.x, p0.y);
  r.y = fmaf(xv.y, p1.x, p1.y);
  r.z = fmaf(xv.z, p2.x, p2.y);
  r.w = fmaf(xv.w, p3.x, p3.y);
  ((float4*)y)[i] = r;
}

// ---------------------------------------------------------------- launch
extern "C" void kernel_launch(void* const* d_in, const int* in_sizes, int n_in,
                              void* d_out, int out_size, void* d_ws, size_t ws_size,
                              hipStream_t stream) {
  const float* x   = (const float*)d_in[0];
  const int*   ei  = (const int*)d_in[1];
  const float* W0  = (const float*)d_in[2];
  const float* as0 = (const float*)d_in[3];
  const float* ad0 = (const float*)d_in[4];
  const float* b0  = (const float*)d_in[5];
  const float* g0  = (const float*)d_in[6];
  const float* be0 = (const float*)d_in[7];
  const float* W1  = (const float*)d_in[8];
  const float* as1 = (const float*)d_in[9];
  const float* ad1 = (const float*)d_in[10];
  const float* b1  = (const float*)d_in[11];
  const float* g1  = (const float*)d_in[12];
  const float* be1 = (const float*)d_in[13];
  const float* W2  = (const float*)d_in[14];
  const float* as2 = (const float*)d_in[15];
  const float* ad2 = (const float*)d_in[16];
  const float* b2  = (const float*)d_in[17];
  const float* g2  = (const float*)d_in[18];
  const float* be2 = (const float*)d_in[19];
  float* out = (float*)d_out;

  // workspace layout
  u16* hb   = (u16*)d_ws;                   // HBROWS*256 bf16 (padded rows)
  u16* abf  = hb + (size_t)HBROWS * 256;    // NN*128 bf16 (layer-0 input)
  u16* ab16 = abf + (size_t)NN * 128;       // NN*256 bf16 (inter-layer, pre-BN)
  u16* Wt0  = ab16 + (size_t)NN * 256;      // 256*128
  u16* Wt1  = Wt0 + 256 * 128;              // 256*256
  u16* Wt2  = Wt1 + 256 * 256;              // 256*256
  float* asrc = (float*)(Wt2 + 256 * 256);  // NN*4
  float* adst = asrc + NN * 4;              // NN*4
  float* aggf = adst + NN * 4;              // NN*256 f32 (final layer only)
  float* bkt  = aggf + (size_t)NN * 256;    // 3 * 32 * 512
  int* cnt    = (int*)(bkt + 3 * 32 * 512); // NN (adjacent -> one memset)
  int* rowst  = cnt + NN;                   // NN+1
  int* cursor = rowst + NN + 1;             // NN
  int* csrc   = cursor + NN;                // ET

  // ---- one memset covers buckets + cnt
  hipMemsetAsync(bkt, 0, (3 * 32 * 512 + NN) * sizeof(float), stream);
  k_castcnt<<<1290, 256, 0, stream>>>(ei, cnt, x, W0, W1, W2, abf, Wt0, Wt1, Wt2);
  k_scan<<<1, 1024, 0, stream>>>(cnt, rowst, cursor, csrc);

  // ---- layer 0 (no input BN; CSR edge-fill rides along as extra blocks)
  k_gemm<128, 0, 1><<<314 + 1250, 256, 0, stream>>>(
      abf, nullptr, nullptr, nullptr, Wt0, as0, ad0, hb, asrc, adst, 4,
      ei, cursor, csrc);
  k_softagg<4, 1><<<NN / 4, 256, 0, stream>>>(rowst, csrc, asrc, adst, hb, b0,
                                              nullptr, ab16, bkt);

  // ---- layer 1 (BN0+ReLU fused into A-load)
  k_gemm<256, 1, 0><<<314, 256, 0, stream>>>(
      ab16, bkt, g0, be0, Wt1, as1, ad1, hb, asrc, adst, 4,
      nullptr, nullptr, nullptr);
  k_softagg<4, 1><<<NN / 4, 256, 0, stream>>>(rowst, csrc, asrc, adst, hb, b1,
                                              nullptr, ab16, bkt + 32 * 512);

  // ---- layer 2 (BN1+ReLU fused; H=1 slot partials)
  k_gemm<256, 1, 0><<<314, 256, 0, stream>>>(
      ab16, bkt + 32 * 512, g1, be1, Wt2, as2, ad2, hb, asrc, adst, 1,
      nullptr, nullptr, nullptr);
  k_softagg<1, 0><<<NN / 4, 256, 0, stream>>>(rowst, csrc, asrc, adst, hb, b2,
                                              aggf, nullptr, bkt + 2 * 32 * 512);

  // ---- final BN (reduce + apply fused) -> out (f32)
  k_bnout<<<NN / 4, 256, 0, stream>>>(bkt + 2 * 32 * 512, g2, be2, aggf, out);
}